// Round 1
// baseline (6110.574 us; speedup 1.0000x reference)
//
#include <hip/hip_runtime.h>
#include <math.h>

#define N_ROWS 32768
#define DIM 256
#define KCODES 8192

// ws layout (float offsets)
#define WS_C2   0
#define WS_X2   8192
#define WS_BD   40960
#define WS_BI   73728
#define WS_L    106496
#define WS_T    139264
#define WS_AVGP 172032
#define WS_CNT  180224
#define WS_SCAL 188416
// scal: 0=mse_sum 1=sent_sum 2=avg_entropy 3=pent 4=nsum

__global__ void rownorm_k(const float* __restrict__ A, float* __restrict__ out, int rows) {
    int w = threadIdx.x >> 6, lane = threadIdx.x & 63;
    int r = blockIdx.x * 4 + w;
    if (r >= rows) return;
    const float4* A4 = (const float4*)(A + (size_t)r * DIM);
    float4 v = A4[lane];
    float s = v.x*v.x + v.y*v.y + v.z*v.z + v.w*v.w;
    #pragma unroll
    for (int off = 32; off >= 1; off >>= 1) s += __shfl_xor(s, off);
    if (lane == 0) out[r] = s;
}

__global__ void init_ncbe_k(const float* __restrict__ cbe, float* __restrict__ outNcbe) {
    int i = blockIdx.x * 256 + threadIdx.x;   // over float4s, 2048*256 = 524288
    float4 v = ((const float4*)cbe)[i];
    v.x *= 0.99f; v.y *= 0.99f; v.z *= 0.99f; v.w *= 0.99f;
    ((float4*)outNcbe)[i] = v;
}

// PASS 1: argmin + online softmax stats (m = -minDist).  PASS 2: avg_probs accumulation.
template<int PASS>
__global__ __launch_bounds__(256) void vq_main(const float* __restrict__ x,
                                               const float* __restrict__ cb,
                                               float* __restrict__ ws,
                                               float* __restrict__ outIdxF) {
    __shared__ __align__(16) float smem[4608];   // xs[64][36] | cs[64][36]; reused as scratch
    float* xs = smem;
    float* cs = smem + 64 * 36;
    const int tid = threadIdx.x;
    const int tx = tid & 15, ty = tid >> 4;
    const int blockRow = blockIdx.x * 64;
    const float* c2 = ws + WS_C2;
    const float* x2 = ws + WS_X2;

    float rowx2[4], pbd4[4], pinv4[4];
    #pragma unroll
    for (int i = 0; i < 4; ++i) {
        int n = blockRow + ty * 4 + i;
        rowx2[i] = x2[n];
        if (PASS == 2) { pbd4[i] = ws[WS_BD + n]; pinv4[i] = 1.0f / ws[WS_L + n]; }
    }
    // running per-row stats (valid only in threads tid<64, row = blockRow + tid)
    float rbd = INFINITY, rbi = 0.f, rl = 0.f, rT = 0.f;

    for (int kt = 0; kt < KCODES / 64; ++kt) {
        float acc[4][4];
        #pragma unroll
        for (int i = 0; i < 4; ++i)
            #pragma unroll
            for (int j = 0; j < 4; ++j) acc[i][j] = 0.f;

        for (int dt = 0; dt < DIM / 32; ++dt) {
            __syncthreads();
            {   // stage x[64][32] and cb[64][32]
                int row = tid >> 2;
                int c0 = (tid & 3) * 8;
                const float* gx = x + (size_t)(blockRow + row) * DIM + dt * 32 + c0;
                const float* gc = cb + (size_t)(kt * 64 + row) * DIM + dt * 32 + c0;
                float4 a0 = *(const float4*)gx;
                float4 a1 = *(const float4*)(gx + 4);
                float4 b0 = *(const float4*)gc;
                float4 b1 = *(const float4*)(gc + 4);
                *(float4*)&xs[row * 36 + c0]     = a0;
                *(float4*)&xs[row * 36 + c0 + 4] = a1;
                *(float4*)&cs[row * 36 + c0]     = b0;
                *(float4*)&cs[row * 36 + c0 + 4] = b1;
            }
            __syncthreads();
            const float4* xs4 = (const float4*)xs;
            const float4* cs4 = (const float4*)cs;
            #pragma unroll
            for (int d4 = 0; d4 < 8; ++d4) {
                float4 a[4], b[4];
                #pragma unroll
                for (int i = 0; i < 4; ++i) a[i] = xs4[(ty * 4 + i) * 9 + d4];
                #pragma unroll
                for (int j = 0; j < 4; ++j) b[j] = cs4[(tx + 16 * j) * 9 + d4];
                #pragma unroll
                for (int i = 0; i < 4; ++i)
                    #pragma unroll
                    for (int j = 0; j < 4; ++j) {
                        acc[i][j] = fmaf(a[i].x, b[j].x, acc[i][j]);
                        acc[i][j] = fmaf(a[i].y, b[j].y, acc[i][j]);
                        acc[i][j] = fmaf(a[i].z, b[j].z, acc[i][j]);
                        acc[i][j] = fmaf(a[i].w, b[j].w, acc[i][j]);
                    }
            }
        }
        __syncthreads();   // tiles consumed; smem becomes reduction scratch

        float c2v[4];
        #pragma unroll
        for (int j = 0; j < 4; ++j) c2v[j] = c2[kt * 64 + 16 * j + tx];

        if (PASS == 1) {
            float* sbd = smem; float* sbi = smem + 1024;
            float* sl  = smem + 2048; float* sT = smem + 3072;
            #pragma unroll
            for (int i = 0; i < 4; ++i) {
                float dist[4];
                float tbd = INFINITY, tbi = 0.f;
                #pragma unroll
                for (int j = 0; j < 4; ++j) {
                    float kf = (float)(kt * 64 + 16 * j + tx);
                    float d2 = fmaf(-2.f, acc[i][j], rowx2[i] + c2v[j]);
                    float dv = sqrtf(fmaxf(d2, 0.f));
                    dist[j] = dv;
                    if (dv < tbd) { tbd = dv; tbi = kf; }   // j ascending => k ascending (first-tie kept)
                }
                float tl = 0.f, tT = 0.f;
                #pragma unroll
                for (int j = 0; j < 4; ++j) {
                    float e = expf(tbd - dist[j]);
                    tl += e;
                    tT += e * (tbd - dist[j]);
                }
                int r = ty * 4 + i;
                sbd[r * 16 + tx] = tbd; sbi[r * 16 + tx] = tbi;
                sl[r * 16 + tx] = tl;   sT[r * 16 + tx] = tT;
            }
            __syncthreads();
            if (tid < 64) {
                int r = tid;
                for (int p = 0; p < 16; ++p) {
                    float pbd = sbd[r * 16 + p], pbi = sbi[r * 16 + p];
                    float pl = sl[r * 16 + p],  pT = sT[r * 16 + p];
                    if (isinf(rbd)) { rbd = pbd; rbi = pbi; rl = pl; rT = pT; }
                    else {
                        float mn = fminf(rbd, pbd);
                        float ar = expf(mn - rbd);
                        float ap = expf(mn - pbd);
                        float nl = ar * rl + ap * pl;
                        float nT = ar * (rT + (mn - rbd) * rl) + ap * (pT + (mn - pbd) * pl);
                        rl = nl; rT = nT;
                        if (pbd < rbd || (pbd == rbd && pbi < rbi)) rbi = pbi;
                        rbd = mn;
                    }
                }
            }
        } else {
            float* sc = smem;   // [64 cols][16 ty]
            float psum[4];
            #pragma unroll
            for (int j = 0; j < 4; ++j) psum[j] = 0.f;
            #pragma unroll
            for (int i = 0; i < 4; ++i)
                #pragma unroll
                for (int j = 0; j < 4; ++j) {
                    float d2 = fmaf(-2.f, acc[i][j], rowx2[i] + c2v[j]);
                    float dv = sqrtf(fmaxf(d2, 0.f));
                    psum[j] += expf(pbd4[i] - dv) * pinv4[i];
                }
            #pragma unroll
            for (int j = 0; j < 4; ++j) sc[(16 * j + tx) * 16 + ty] = psum[j];
            __syncthreads();
            if (tid < 64) {
                float s = 0.f;
                for (int t = 0; t < 16; ++t) s += sc[tid * 16 + t];
                atomicAdd(&ws[WS_AVGP + kt * 64 + tid], s);
            }
        }
    }

    if (PASS == 1 && tid < 64) {
        int n = blockRow + tid;
        ws[WS_BD + n] = rbd;
        ((int*)ws)[WS_BI + n] = (int)rbi;
        ws[WS_L + n] = rl;
        ws[WS_T + n] = rT;
        outIdxF[n] = rbi;
        atomicAdd(&ws[WS_SCAL + 0], rbd * rbd);              // d2_min
        atomicAdd(&ws[WS_SCAL + 1], rT / rl - logf(rl));     // sum p*logp for this row
    }
}

__global__ void gather_scatter_k(const float* __restrict__ x, const float* __restrict__ cb,
                                 const float* __restrict__ ws, float* __restrict__ outQ,
                                 float* __restrict__ outNcbe, float* __restrict__ counts) {
    int w = threadIdx.x >> 6, lane = threadIdx.x & 63;
    int n = blockIdx.x * 4 + w;
    int idx = ((const int*)ws)[WS_BI + n];
    const float4* x4 = (const float4*)(x + (size_t)n * DIM);
    const float4* c4 = (const float4*)(cb + (size_t)idx * DIM);
    float4 xv = x4[lane], cv = c4[lane];
    float4 q;
    q.x = xv.x + (cv.x - xv.x); q.y = xv.y + (cv.y - xv.y);
    q.z = xv.z + (cv.z - xv.z); q.w = xv.w + (cv.w - xv.w);
    ((float4*)(outQ + (size_t)n * DIM))[lane] = q;
    float* dst = outNcbe + (size_t)idx * DIM + lane * 4;
    const float g = 1.0f - 0.99f;
    atomicAdd(dst + 0, g * xv.x); atomicAdd(dst + 1, g * xv.y);
    atomicAdd(dst + 2, g * xv.z); atomicAdd(dst + 3, g * xv.w);
    if (lane == 0) atomicAdd(&((float*)counts)[idx], 1.0f);
}

__global__ void stats_k(const float* __restrict__ cse, float* __restrict__ ws,
                        float* __restrict__ outNcse) {
    int k = blockIdx.x * 256 + threadIdx.x;
    float cnt = ws[WS_CNT + k];
    float ncse = 0.99f * cse[k] + (1.0f - 0.99f) * cnt;
    outNcse[k] = ncse;
    atomicAdd(&ws[WS_SCAL + 4], ncse);
    float ap = ws[WS_AVGP + k] * (1.0f / N_ROWS);
    atomicAdd(&ws[WS_SCAL + 2], -(ap * logf(ap + 1e-5f)));     // avg_entropy
    float app = cnt * (1.0f / N_ROWS);
    atomicAdd(&ws[WS_SCAL + 3], -(app * logf(app + 1e-10f)));  // perplexity exponent
}

__global__ void newcb_k(const float* __restrict__ ws, const float* __restrict__ outNcse,
                        const float* __restrict__ outNcbe, float* __restrict__ outNc) {
    int w = threadIdx.x >> 6, lane = threadIdx.x & 63;
    int k = blockIdx.x * 4 + w;
    float n = ws[WS_SCAL + 4];
    float ncse = outNcse[k];
    float smoothed = (ncse + 1e-5f) / (n + (float)KCODES * 1e-5f) * n;
    float inv = 1.0f / smoothed;
    float4 v = ((const float4*)(outNcbe + (size_t)k * DIM))[lane];
    v.x *= inv; v.y *= inv; v.z *= inv; v.w *= inv;
    ((float4*)(outNc + (size_t)k * DIM))[lane] = v;
}

__global__ void finalize_k(const float* __restrict__ ws, float* __restrict__ outLoss,
                           float* __restrict__ outPerp) {
    float mse = ws[WS_SCAL + 0] * (1.0f / ((float)N_ROWS * 256.0f));
    float sent = -ws[WS_SCAL + 1] * (1.0f / (float)N_ROWS);   // sample_entropy
    float ent = sent - ws[WS_SCAL + 2];
    outLoss[0] = (0.25f + 1.0f) * mse + 0.1f * ent;
    outPerp[0] = expf(ws[WS_SCAL + 3]);
}

extern "C" void kernel_launch(void* const* d_in, const int* in_sizes, int n_in,
                              void* d_out, int out_size, void* d_ws, size_t ws_size,
                              hipStream_t stream) {
    const float* x   = (const float*)d_in[0];
    const float* cb  = (const float*)d_in[1];
    const float* cse = (const float*)d_in[2];
    const float* cbe = (const float*)d_in[3];
    float* out = (float*)d_out;
    float* ws  = (float*)d_ws;

    float* outQ    = out;                  // [32768,256]
    float* outLoss = out + 8388608;        // scalar
    float* outPerp = out + 8388609;        // scalar
    float* outIdxF = out + 8388610;        // [32768] indices as float
    float* outNc   = out + 8421378;        // [8192,256]
    float* outNcse = out + 10518530;       // [8192]
    float* outNcbe = out + 10526722;       // [8192,256]

    hipMemsetAsync(ws + WS_AVGP, 0, (8192 + 8192 + 8) * sizeof(float), stream);
    rownorm_k<<<KCODES / 4, 256, 0, stream>>>(cb, ws + WS_C2, KCODES);
    rownorm_k<<<N_ROWS / 4, 256, 0, stream>>>(x, ws + WS_X2, N_ROWS);
    init_ncbe_k<<<2048, 256, 0, stream>>>(cbe, outNcbe);
    vq_main<1><<<N_ROWS / 64, 256, 0, stream>>>(x, cb, ws, outIdxF);
    vq_main<2><<<N_ROWS / 64, 256, 0, stream>>>(x, cb, ws, outIdxF);
    gather_scatter_k<<<N_ROWS / 4, 256, 0, stream>>>(x, cb, ws, outQ, outNcbe, ws + WS_CNT);
    stats_k<<<KCODES / 256, 256, 0, stream>>>(cse, ws, outNcse);
    newcb_k<<<KCODES / 4, 256, 0, stream>>>(ws, outNcse, outNcbe, outNc);
    finalize_k<<<1, 1, 0, stream>>>(ws, outLoss, outPerp);
}

// Round 2
// 2714.880 us; speedup vs baseline: 2.2508x; 2.2508x over previous
//
#include <hip/hip_runtime.h>
#include <math.h>

#define N_ROWS 32768
#define DIM 256
#define KCODES 8192

#define BM 128
#define BN 256
#define BK 32
#define NKT (KCODES / BN)   // 32
#define NDT (DIM / BK)      // 8
#define TAU 1e-3f

// ws layout (float offsets)
#define WS_C2    0
#define WS_X2    8192
#define WS_BD    40960
#define WS_BI    73728
#define WS_L     106496
#define WS_FLAGL 139264      // flagged-row list (reuses old T slot), 32768 ints
#define WS_AVGP  172032
#define WS_CNT   180224
#define WS_SCAL  188416      // 0=mse 1=sum p*logp 2=avg_entropy 3=pent 4=nsum
#define WS_FLAGN 188424      // int count

typedef __bf16 bf16x8 __attribute__((ext_vector_type(8)));
typedef float  f32x4  __attribute__((ext_vector_type(4)));

__global__ void rownorm_k(const float* __restrict__ A, float* __restrict__ out, int rows) {
    int w = threadIdx.x >> 6, lane = threadIdx.x & 63;
    int r = blockIdx.x * 4 + w;
    if (r >= rows) return;
    const float4* A4 = (const float4*)(A + (size_t)r * DIM);
    float4 v = A4[lane];
    float s = v.x*v.x + v.y*v.y + v.z*v.z + v.w*v.w;
    #pragma unroll
    for (int off = 32; off >= 1; off >>= 1) s += __shfl_xor(s, off);
    if (lane == 0) out[r] = s;
}

__global__ void init_ncbe_k(const float* __restrict__ cbe, float* __restrict__ outNcbe) {
    int i = blockIdx.x * 256 + threadIdx.x;
    float4 v = ((const float4*)cbe)[i];
    v.x *= 0.99f; v.y *= 0.99f; v.z *= 0.99f; v.w *= 0.99f;
    ((float4*)outNcbe)[i] = v;
}

// split f32 -> hi bf16 (truncate) + lo bf16 (truncate of remainder); 8 elems
__device__ __forceinline__ void cvt_store8(ushort* hdst, ushort* ldst, const float* __restrict__ g) {
    float4 v0 = *(const float4*)g;
    float4 v1 = *(const float4*)(g + 4);
    float vv[8] = {v0.x, v0.y, v0.z, v0.w, v1.x, v1.y, v1.z, v1.w};
    uint h[4], lo[4];
    #pragma unroll
    for (int p = 0; p < 4; ++p) {
        uint ua = __float_as_uint(vv[2*p]), ub = __float_as_uint(vv[2*p+1]);
        uint ha = ua & 0xFFFF0000u, hb = ub & 0xFFFF0000u;
        float ra = vv[2*p]     - __uint_as_float(ha);
        float rb = vv[2*p + 1] - __uint_as_float(hb);
        h[p]  = hb | (ha >> 16);
        lo[p] = (__float_as_uint(rb) & 0xFFFF0000u) | (__float_as_uint(ra) >> 16);
    }
    *(uint4*)hdst = make_uint4(h[0], h[1], h[2], h[3]);
    *(uint4*)ldst = make_uint4(lo[0], lo[1], lo[2], lo[3]);
}

// merge two candidate-set summaries: (min dist b1, its idx, 2nd-best b2, l=sum e^{b1-d}, T=sum e^{b1-d}(b1-d))
__device__ __forceinline__ void online_merge(float& b1, int& i1, float& b2, float& l, float& T,
                                             float nb1, int ni1, float nb2, float nl, float nT) {
    float m  = fminf(b1, nb1);
    float fa = __expf(m - b1);
    float fb = __expf(m - nb1);
    float L  = fa * l + fb * nl;
    float TT = fa * (T + (m - b1) * l) + fb * (nT + (m - nb1) * nl);
    float losing = fmaxf(b1, nb1);
    float B2 = fminf(fminf(b2, nb2), losing);
    if (nb1 < b1 || (nb1 == b1 && ni1 < i1)) i1 = ni1;
    b1 = m; b2 = B2; l = L; T = TT;
}

// PASS 1: argmin (+2nd best) + online softmax stats.  PASS 2: avg_probs accumulation.
template<int PASS>
__global__ __launch_bounds__(512, 2) void vq_mfma(const float* __restrict__ x,
                                                  const float* __restrict__ cb,
                                                  float* __restrict__ ws) {
    __shared__ __align__(16) ushort sCH[BN * BK];  // codes hi  [256][32]
    __shared__ __align__(16) ushort sCL[BN * BK];  // codes lo
    __shared__ __align__(16) ushort sXH[BM * BK];  // x hi      [128][32]
    __shared__ __align__(16) ushort sXL[BM * BK];  // x lo
    __shared__ float sb1[BM][4]; __shared__ int si1[BM][4];
    __shared__ float sb2[BM][4]; __shared__ float slv[BM][4]; __shared__ float sTv[BM][4];
    __shared__ float red[2];

    const int tid  = threadIdx.x;
    const int lane = tid & 63, wid = tid >> 6;
    const int wcode = wid & 3, wx = wid >> 2;      // 4 code-groups x 2 xrow-groups of waves
    const int l15 = lane & 15, l4 = lane >> 4;
    const int blockRow = blockIdx.x * BM;

    const float* c2  = ws + WS_C2;
    const float* x2p = ws + WS_X2;

    float x2v[4], bdv[4], invl[4];
    #pragma unroll
    for (int n = 0; n < 4; ++n) {
        int rl = wx * 64 + n * 16 + l15;
        x2v[n] = x2p[blockRow + rl];
        if (PASS == 2) {
            bdv[n]  = ws[WS_BD + blockRow + rl];
            invl[n] = 1.0f / ws[WS_L + blockRow + rl];
        }
    }
    float rb1[4], rb2[4], rlv[4], rTv[4]; int ri1[4];
    #pragma unroll
    for (int n = 0; n < 4; ++n) { rb1[n] = 1e30f; rb2[n] = 1e30f; rlv[n] = 0.f; rTv[n] = 0.f; ri1[n] = 0; }

    for (int kt = 0; kt < NKT; ++kt) {
        f32x4 acc[4][4];
        #pragma unroll
        for (int m = 0; m < 4; ++m)
            #pragma unroll
            for (int n = 0; n < 4; ++n) acc[m][n] = (f32x4){0.f, 0.f, 0.f, 0.f};

        for (int dt = 0; dt < NDT; ++dt) {
            __syncthreads();
            {   // x: 512 chunks of 8 elems
                int row = tid >> 2, c = tid & 3;
                cvt_store8(&sXH[row * 32 + c * 8], &sXL[row * 32 + c * 8],
                           x + (size_t)(blockRow + row) * DIM + dt * BK + c * 8);
            }
            #pragma unroll
            for (int j = 0; j < 2; ++j) {   // cb: 1024 chunks
                int cid = tid + 512 * j, row = cid >> 2, c = cid & 3;
                cvt_store8(&sCH[row * 32 + c * 8], &sCL[row * 32 + c * 8],
                           cb + (size_t)(kt * BN + row) * DIM + dt * BK + c * 8);
            }
            __syncthreads();

            bf16x8 ah[4], al[4], bh[4], bl[4];
            #pragma unroll
            for (int m = 0; m < 4; ++m) {
                int ro = (wcode * 64 + m * 16 + l15) * 32 + l4 * 8;
                ah[m] = __builtin_bit_cast(bf16x8, *(const uint4*)&sCH[ro]);
                al[m] = __builtin_bit_cast(bf16x8, *(const uint4*)&sCL[ro]);
            }
            #pragma unroll
            for (int n = 0; n < 4; ++n) {
                int ro = (wx * 64 + n * 16 + l15) * 32 + l4 * 8;
                bh[n] = __builtin_bit_cast(bf16x8, *(const uint4*)&sXH[ro]);
                bl[n] = __builtin_bit_cast(bf16x8, *(const uint4*)&sXL[ro]);
            }
            #pragma unroll
            for (int m = 0; m < 4; ++m)
                #pragma unroll
                for (int n = 0; n < 4; ++n) {
                    acc[m][n] = __builtin_amdgcn_mfma_f32_16x16x32_bf16(ah[m], bh[n], acc[m][n], 0, 0, 0);
                    acc[m][n] = __builtin_amdgcn_mfma_f32_16x16x32_bf16(ah[m], bl[n], acc[m][n], 0, 0, 0);
                    acc[m][n] = __builtin_amdgcn_mfma_f32_16x16x32_bf16(al[m], bh[n], acc[m][n], 0, 0, 0);
                }
        }

        // epilogue: lane holds D[code=(l4*4+r)+16m][xrow=l15+16n]
        const int cbase = kt * BN + wcode * 64 + l4 * 4;
        float c2v[4][4];
        #pragma unroll
        for (int m = 0; m < 4; ++m)
            #pragma unroll
            for (int r = 0; r < 4; ++r) c2v[m][r] = c2[cbase + m * 16 + r];

        if (PASS == 1) {
            #pragma unroll
            for (int n = 0; n < 4; ++n) {
                float dsv[4][4];
                float b1 = 1e30f, b2 = 1e30f; int i1 = 0;
                #pragma unroll
                for (int m = 0; m < 4; ++m)
                    #pragma unroll
                    for (int r = 0; r < 4; ++r) {
                        float d2 = fmaf(-2.f, acc[m][n][r], x2v[n] + c2v[m][r]);
                        float dv = sqrtf(fmaxf(d2, 0.f));
                        dsv[m][r] = dv;
                        bool better = dv < b1;
                        b2 = better ? b1 : fminf(b2, dv);
                        if (better) { b1 = dv; i1 = cbase + m * 16 + r; }
                    }
                float ls = 0.f, ts = 0.f;
                #pragma unroll
                for (int m = 0; m < 4; ++m)
                    #pragma unroll
                    for (int r = 0; r < 4; ++r) {
                        float e = __expf(b1 - dsv[m][r]);
                        ls += e;
                        ts = fmaf(e, b1 - dsv[m][r], ts);
                    }
                online_merge(rb1[n], ri1[n], rb2[n], rlv[n], rTv[n], b1, i1, b2, ls, ts);
            }
        } else {
            float ps[4][4];
            #pragma unroll
            for (int m = 0; m < 4; ++m)
                #pragma unroll
                for (int r = 0; r < 4; ++r) ps[m][r] = 0.f;
            #pragma unroll
            for (int n = 0; n < 4; ++n)
                #pragma unroll
                for (int m = 0; m < 4; ++m)
                    #pragma unroll
                    for (int r = 0; r < 4; ++r) {
                        float d2 = fmaf(-2.f, acc[m][n][r], x2v[n] + c2v[m][r]);
                        float dv = sqrtf(fmaxf(d2, 0.f));
                        ps[m][r] = fmaf(__expf(bdv[n] - dv), invl[n], ps[m][r]);
                    }
            #pragma unroll
            for (int m = 0; m < 4; ++m)
                #pragma unroll
                for (int r = 0; r < 4; ++r) {
                    float v = ps[m][r];
                    v += __shfl_xor(v, 1); v += __shfl_xor(v, 2);
                    v += __shfl_xor(v, 4); v += __shfl_xor(v, 8);
                    ps[m][r] = v;
                }
            if (l15 == 0) {
                #pragma unroll
                for (int m = 0; m < 4; ++m)
                    #pragma unroll
                    for (int r = 0; r < 4; ++r)
                        atomicAdd(&ws[WS_AVGP + cbase + m * 16 + r], ps[m][r]);
            }
        }
    }

    if (PASS == 1) {
        #pragma unroll
        for (int n = 0; n < 4; ++n) {
            #pragma unroll
            for (int off = 16; off <= 32; off <<= 1) {
                float ob1 = __shfl_xor(rb1[n], off);
                int   oi  = __shfl_xor(ri1[n], off);
                float ob2 = __shfl_xor(rb2[n], off);
                float ol  = __shfl_xor(rlv[n], off);
                float oT  = __shfl_xor(rTv[n], off);
                online_merge(rb1[n], ri1[n], rb2[n], rlv[n], rTv[n], ob1, oi, ob2, ol, oT);
            }
        }
        if (l4 == 0) {
            #pragma unroll
            for (int n = 0; n < 4; ++n) {
                int rl = wx * 64 + n * 16 + l15;
                sb1[rl][wcode] = rb1[n]; si1[rl][wcode] = ri1[n];
                sb2[rl][wcode] = rb2[n]; slv[rl][wcode] = rlv[n]; sTv[rl][wcode] = rTv[n];
            }
        }
        __syncthreads();
        if (tid < BM) {
            float b1 = sb1[tid][0]; int i1 = si1[tid][0];
            float b2 = sb2[tid][0]; float L = slv[tid][0]; float T = sTv[tid][0];
            #pragma unroll
            for (int s = 1; s < 4; ++s)
                online_merge(b1, i1, b2, L, T, sb1[tid][s], si1[tid][s], sb2[tid][s], slv[tid][s], sTv[tid][s]);
            int grow = blockRow + tid;
            ws[WS_BD + grow] = b1;
            ((int*)ws)[WS_BI + grow] = i1;
            ws[WS_L + grow] = L;
            if (b2 - b1 < TAU) {
                int p = atomicAdd(((int*)ws) + WS_FLAGN, 1);
                ((int*)ws)[WS_FLAGL + p] = grow;
            }
            float sval = T / L - __logf(L);   // sum_k p*logp for this row
            #pragma unroll
            for (int off = 32; off >= 1; off >>= 1) sval += __shfl_xor(sval, off);
            if ((tid & 63) == 0) red[tid >> 6] = sval;
        }
        __syncthreads();
        if (tid == 0) atomicAdd(&ws[WS_SCAL + 1], red[0] + red[1]);
    }
}

// exact f32 argmin recompute for rows with small margin
__global__ void fixup_k(const float* __restrict__ x, const float* __restrict__ cb,
                        float* __restrict__ ws) {
    __shared__ float xr[DIM];
    __shared__ float rbd[256]; __shared__ int rbi[256];
    const int tid = threadIdx.x;
    const int nf = ((const int*)ws)[WS_FLAGN];
    for (int f = blockIdx.x; f < nf; f += gridDim.x) {
        int row = ((const int*)ws)[WS_FLAGL + f];
        __syncthreads();
        if (tid < 64) ((float4*)xr)[tid] = ((const float4*)(x + (size_t)row * DIM))[tid];
        __syncthreads();
        float x2r = ws[WS_X2 + row];
        float best = 1e30f; int bi = 0;
        for (int c = tid; c < KCODES; c += 256) {
            const float4* crow = (const float4*)(cb + (size_t)c * DIM);
            float dot = 0.f;
            for (int d4 = 0; d4 < 64; ++d4) {
                float4 cv = crow[d4]; float4 xv = ((const float4*)xr)[d4];
                dot = fmaf(cv.x, xv.x, dot); dot = fmaf(cv.y, xv.y, dot);
                dot = fmaf(cv.z, xv.z, dot); dot = fmaf(cv.w, xv.w, dot);
            }
            float d2 = fmaf(-2.f, dot, x2r + ws[WS_C2 + c]);
            float dv = sqrtf(fmaxf(d2, 0.f));
            if (dv < best) { best = dv; bi = c; }
        }
        rbd[tid] = best; rbi[tid] = bi;
        for (int s = 128; s > 0; s >>= 1) {
            __syncthreads();
            if (tid < s) {
                float ob = rbd[tid + s]; int oi = rbi[tid + s];
                if (ob < rbd[tid] || (ob == rbd[tid] && oi < rbi[tid])) { rbd[tid] = ob; rbi[tid] = oi; }
            }
        }
        __syncthreads();
        if (tid == 0) ((int*)ws)[WS_BI + row] = rbi[0];
    }
}

__global__ void gather_k(const float* __restrict__ x, const float* __restrict__ cb,
                         float* __restrict__ ws, float* __restrict__ outQ,
                         float* __restrict__ outNcbe, float* __restrict__ outIdxF) {
    __shared__ float red2[4];
    const int tid = threadIdx.x, w = tid >> 6, lane = tid & 63;
    float msum = 0.f;
    for (int it = 0; it < 8; ++it) {
        int n = blockIdx.x * 32 + it * 4 + w;
        int idx = ((const int*)ws)[WS_BI + n];
        float4 xv = ((const float4*)(x + (size_t)n * DIM))[lane];
        float4 cv = ((const float4*)(cb + (size_t)idx * DIM))[lane];
        float4 q;
        q.x = xv.x + (cv.x - xv.x); q.y = xv.y + (cv.y - xv.y);
        q.z = xv.z + (cv.z - xv.z); q.w = xv.w + (cv.w - xv.w);
        ((float4*)(outQ + (size_t)n * DIM))[lane] = q;
        float* dst = outNcbe + (size_t)idx * DIM + lane * 4;
        const float g = 0.01f;
        atomicAdd(dst + 0, g * xv.x); atomicAdd(dst + 1, g * xv.y);
        atomicAdd(dst + 2, g * xv.z); atomicAdd(dst + 3, g * xv.w);
        float dx = cv.x - xv.x, dy = cv.y - xv.y, dz = cv.z - xv.z, dw = cv.w - xv.w;
        float s = dx*dx + dy*dy + dz*dz + dw*dw;
        #pragma unroll
        for (int off = 32; off >= 1; off >>= 1) s += __shfl_xor(s, off);
        if (lane == 0) {
            msum += s;
            atomicAdd(&ws[WS_CNT + idx], 1.0f);
            outIdxF[n] = (float)idx;
        }
    }
    if (lane == 0) red2[w] = msum;
    __syncthreads();
    if (tid == 0) atomicAdd(&ws[WS_SCAL + 0], red2[0] + red2[1] + red2[2] + red2[3]);
}

__global__ void stats_k(const float* __restrict__ cse, float* __restrict__ ws,
                        float* __restrict__ outNcse) {
    int tid = threadIdx.x, lane = tid & 63;
    int k = blockIdx.x * 256 + tid;
    float cnt = ws[WS_CNT + k];
    float ncse = 0.99f * cse[k] + 0.01f * cnt;
    outNcse[k] = ncse;
    float ap  = ws[WS_AVGP + k] * (1.0f / N_ROWS);
    float ae  = -(ap * __logf(ap + 1e-5f));
    float app = cnt * (1.0f / N_ROWS);
    float pe  = -(app * __logf(app + 1e-10f));
    #pragma unroll
    for (int off = 32; off >= 1; off >>= 1) {
        ncse += __shfl_xor(ncse, off);
        ae   += __shfl_xor(ae, off);
        pe   += __shfl_xor(pe, off);
    }
    if (lane == 0) {
        atomicAdd(&ws[WS_SCAL + 4], ncse);
        atomicAdd(&ws[WS_SCAL + 2], ae);
        atomicAdd(&ws[WS_SCAL + 3], pe);
    }
}

__global__ void newcb_k(const float* __restrict__ ws, const float* __restrict__ outNcse,
                        const float* __restrict__ outNcbe, float* __restrict__ outNc) {
    int w = threadIdx.x >> 6, lane = threadIdx.x & 63;
    int k = blockIdx.x * 4 + w;
    float n = ws[WS_SCAL + 4];
    float ncse = outNcse[k];
    float smoothed = (ncse + 1e-5f) / (n + (float)KCODES * 1e-5f) * n;
    float inv = 1.0f / smoothed;
    float4 v = ((const float4*)(outNcbe + (size_t)k * DIM))[lane];
    v.x *= inv; v.y *= inv; v.z *= inv; v.w *= inv;
    ((float4*)(outNc + (size_t)k * DIM))[lane] = v;
}

__global__ void finalize_k(const float* __restrict__ ws, float* __restrict__ outLoss,
                           float* __restrict__ outPerp) {
    float mse  = ws[WS_SCAL + 0] * (1.0f / ((float)N_ROWS * 256.0f));
    float sent = -ws[WS_SCAL + 1] * (1.0f / (float)N_ROWS);
    float ent  = sent - ws[WS_SCAL + 2];
    outLoss[0] = 1.25f * mse + 0.1f * ent;
    outPerp[0] = expf(ws[WS_SCAL + 3]);
}

extern "C" void kernel_launch(void* const* d_in, const int* in_sizes, int n_in,
                              void* d_out, int out_size, void* d_ws, size_t ws_size,
                              hipStream_t stream) {
    const float* x   = (const float*)d_in[0];
    const float* cb  = (const float*)d_in[1];
    const float* cse = (const float*)d_in[2];
    const float* cbe = (const float*)d_in[3];
    float* out = (float*)d_out;
    float* ws  = (float*)d_ws;

    float* outQ    = out;
    float* outLoss = out + 8388608;
    float* outPerp = out + 8388609;
    float* outIdxF = out + 8388610;
    float* outNc   = out + 8421378;
    float* outNcse = out + 10518530;
    float* outNcbe = out + 10526722;

    hipMemsetAsync(ws + WS_AVGP, 0, (size_t)(WS_FLAGN + 1 - WS_AVGP) * sizeof(float), stream);
    rownorm_k<<<KCODES / 4, 256, 0, stream>>>(cb, ws + WS_C2, KCODES);
    rownorm_k<<<N_ROWS / 4, 256, 0, stream>>>(x, ws + WS_X2, N_ROWS);
    init_ncbe_k<<<2048, 256, 0, stream>>>(cbe, outNcbe);
    vq_mfma<1><<<N_ROWS / BM, 512, 0, stream>>>(x, cb, ws);
    vq_mfma<2><<<N_ROWS / BM, 512, 0, stream>>>(x, cb, ws);
    fixup_k<<<64, 256, 0, stream>>>(x, cb, ws);
    gather_k<<<1024, 256, 0, stream>>>(x, cb, ws, outQ, outNcbe, outIdxF);
    stats_k<<<KCODES / 256, 256, 0, stream>>>(cse, ws, outNcse);
    newcb_k<<<KCODES / 4, 256, 0, stream>>>(ws, outNcse, outNcbe, outNc);
    finalize_k<<<1, 1, 0, stream>>>(ws, outLoss, outPerp);
}

// Round 3
// 2713.292 us; speedup vs baseline: 2.2521x; 1.0006x over previous
//
#include <hip/hip_runtime.h>
#include <math.h>

#define N_ROWS 32768
#define DIM 256
#define KCODES 8192

#define BM 128
#define BN 256
#define BK 32
#define NKT (KCODES / BN)   // 32
#define NDT (DIM / BK)      // 8
#define NSTEP (NKT * NDT)   // 256
#define TAU 1e-3f

// ws layout (float offsets)
#define WS_C2    0
#define WS_X2    8192
#define WS_BD    40960
#define WS_BI    73728
#define WS_L     106496
#define WS_FLAGL 139264
#define WS_AVGP  172032
#define WS_CNT   180224
#define WS_SCAL  188416      // 0=mse 1=sum p*logp 2=avg_entropy 3=pent 4=nsum
#define WS_FLAGN 188424

typedef __bf16 bf16x8 __attribute__((ext_vector_type(8)));
typedef float  f32x4  __attribute__((ext_vector_type(4)));

__device__ __forceinline__ void gll16(const void* g, void* l) {
    __builtin_amdgcn_global_load_lds((const __attribute__((address_space(1))) void*)g,
                                     (__attribute__((address_space(3))) void*)l, 16, 0, 0);
}

__global__ void rownorm_k(const float* __restrict__ A, float* __restrict__ out, int rows) {
    int w = threadIdx.x >> 6, lane = threadIdx.x & 63;
    int r = blockIdx.x * 4 + w;
    if (r >= rows) return;
    const float4* A4 = (const float4*)(A + (size_t)r * DIM);
    float4 v = A4[lane];
    float s = v.x*v.x + v.y*v.y + v.z*v.z + v.w*v.w;
    #pragma unroll
    for (int off = 32; off >= 1; off >>= 1) s += __shfl_xor(s, off);
    if (lane == 0) out[r] = s;
}

// split f32 -> hi bf16 (truncate) + lo bf16 (truncate of remainder), 8 elems/thread
__global__ void split_k(const float* __restrict__ src, ushort* __restrict__ h,
                        ushort* __restrict__ l) {
    int i = blockIdx.x * 256 + threadIdx.x;
    const float4* s4 = (const float4*)src;
    float4 v0 = s4[2 * i], v1 = s4[2 * i + 1];
    float vv[8] = {v0.x, v0.y, v0.z, v0.w, v1.x, v1.y, v1.z, v1.w};
    uint hw[4], lw[4];
    #pragma unroll
    for (int p = 0; p < 4; ++p) {
        uint ua = __float_as_uint(vv[2*p]), ub = __float_as_uint(vv[2*p+1]);
        uint ha = ua & 0xFFFF0000u, hb = ub & 0xFFFF0000u;
        float ra = vv[2*p]     - __uint_as_float(ha);
        float rb = vv[2*p + 1] - __uint_as_float(hb);
        hw[p] = hb | (ha >> 16);
        lw[p] = (__float_as_uint(rb) & 0xFFFF0000u) | (__float_as_uint(ra) >> 16);
    }
    ((uint4*)h)[i] = make_uint4(hw[0], hw[1], hw[2], hw[3]);
    ((uint4*)l)[i] = make_uint4(lw[0], lw[1], lw[2], lw[3]);
}

__global__ void init_ncbe_k(const float* __restrict__ cbe, float* __restrict__ outNcbe) {
    int i = blockIdx.x * 256 + threadIdx.x;
    float4 v = ((const float4*)cbe)[i];
    v.x *= 0.99f; v.y *= 0.99f; v.z *= 0.99f; v.w *= 0.99f;
    ((float4*)outNcbe)[i] = v;
}

__device__ __forceinline__ void online_merge(float& b1, int& i1, float& b2, float& l, float& T,
                                             float nb1, int ni1, float nb2, float nl, float nT) {
    float m  = fminf(b1, nb1);
    float fa = __expf(m - b1);
    float fb = __expf(m - nb1);
    float L  = fa * l + fb * nl;
    float TT = fa * (T + (m - b1) * l) + fb * (nT + (m - nb1) * nl);
    float losing = fmaxf(b1, nb1);
    float B2 = fminf(fminf(b2, nb2), losing);
    if (nb1 < b1 || (nb1 == b1 && ni1 < i1)) i1 = ni1;
    b1 = m; b2 = B2; l = L; T = TT;
}

// stage tile-step t into ldsbuf: cbh[256][32] | cbl | xh[128][32] | xl  (swizzled source)
__device__ __forceinline__ void stage(int t, ushort* buf,
                                      const ushort* __restrict__ xh, const ushort* __restrict__ xl,
                                      const ushort* __restrict__ ch, const ushort* __restrict__ cl,
                                      int blockRow, int wid, int lane) {
    const int kt = t >> 3, dt = t & 7;
    const int rsub = lane >> 2, s = lane & 3;
    #pragma unroll
    for (int i = 0; i < 6; ++i) {
        const int c = wid * 6 + i;
        if (c < 32) {
            const int half = c >> 4;          // 0=hi 1=lo
            const int cc = c & 15;
            const int row = cc * 16 + rsub;   // 0..255
            const int col = s ^ ((row >> 2) & 3);
            const ushort* src = (half ? cl : ch) + (((size_t)(kt * 256 + row)) << 8)
                                + (dt << 5) + (col << 3);
            ushort* dst = buf + (half << 13) + (cc << 9);
            gll16(src, dst);
        } else {
            const int half = (c >> 3) & 1;    // 32-39 hi, 40-47 lo
            const int cc = c & 7;
            const int row = cc * 16 + rsub;   // 0..127
            const int col = s ^ ((row >> 2) & 3);
            const ushort* src = (half ? xl : xh) + (((size_t)(blockRow + row)) << 8)
                                + (dt << 5) + (col << 3);
            ushort* dst = buf + 16384 + (half << 12) + (cc << 9);
            gll16(src, dst);
        }
    }
}

// PASS 1: argmin (+2nd best) + online softmax stats.  PASS 2: avg_probs accumulation.
template<int PASS>
__global__ __launch_bounds__(512) void vq_mfma(const ushort* __restrict__ xh,
                                               const ushort* __restrict__ xl,
                                               const ushort* __restrict__ ch,
                                               const ushort* __restrict__ cl,
                                               float* __restrict__ ws) {
    __shared__ __align__(16) ushort lds[2][24576];   // 96 KB: 2 x (cbh|cbl|xh|xl)
    __shared__ float sb1[BM][4]; __shared__ int si1[BM][4];
    __shared__ float sb2[BM][4]; __shared__ float slv[BM][4]; __shared__ float sTv[BM][4];
    __shared__ float red[2];

    const int tid  = threadIdx.x;
    const int lane = tid & 63, wid = tid >> 6;
    const int wcode = wid & 3, wx = wid >> 2;
    const int l15 = lane & 15, l4 = lane >> 4;
    const int blockRow = blockIdx.x * BM;
    const int fsw = ((l4 ^ (l15 >> 2)) << 3);

    const float* c2  = ws + WS_C2;
    const float* x2p = ws + WS_X2;

    float x2v[4], bdv[4], invl[4];
    #pragma unroll
    for (int n = 0; n < 4; ++n) {
        int rl = wx * 64 + n * 16 + l15;
        x2v[n] = x2p[blockRow + rl];
        if (PASS == 2) {
            bdv[n]  = ws[WS_BD + blockRow + rl];
            invl[n] = 1.0f / ws[WS_L + blockRow + rl];
        }
    }
    float rb1[4], rb2[4], rlv[4], rTv[4]; int ri1[4];
    #pragma unroll
    for (int n = 0; n < 4; ++n) { rb1[n] = 1e30f; rb2[n] = 1e30f; rlv[n] = 0.f; rTv[n] = 0.f; ri1[n] = 0; }

    stage(0, lds[0], xh, xl, ch, cl, blockRow, wid, lane);
    __syncthreads();

    for (int kt = 0; kt < NKT; ++kt) {
        f32x4 acc[4][4];
        #pragma unroll
        for (int m = 0; m < 4; ++m)
            #pragma unroll
            for (int n = 0; n < 4; ++n) acc[m][n] = (f32x4){0.f, 0.f, 0.f, 0.f};

        #pragma unroll
        for (int dt = 0; dt < NDT; ++dt) {
            const int t = kt * 8 + dt;
            if (t + 1 < NSTEP)
                stage(t + 1, lds[(t + 1) & 1], xh, xl, ch, cl, blockRow, wid, lane);

            const ushort* bb = lds[t & 1];
            bf16x8 bhf[4], blf[4];
            #pragma unroll
            for (int n = 0; n < 4; ++n) {
                int off = (wx * 64 + n * 16 + l15) * 32 + fsw;
                bhf[n] = __builtin_bit_cast(bf16x8, *(const uint4*)(bb + 16384 + off));
                blf[n] = __builtin_bit_cast(bf16x8, *(const uint4*)(bb + 20480 + off));
            }
            #pragma unroll
            for (int m = 0; m < 4; ++m) {
                int off = (wcode * 64 + m * 16 + l15) * 32 + fsw;
                bf16x8 ahf = __builtin_bit_cast(bf16x8, *(const uint4*)(bb + off));
                bf16x8 alf = __builtin_bit_cast(bf16x8, *(const uint4*)(bb + 8192 + off));
                #pragma unroll
                for (int n = 0; n < 4; ++n) {
                    acc[m][n] = __builtin_amdgcn_mfma_f32_16x16x32_bf16(ahf, bhf[n], acc[m][n], 0, 0, 0);
                    acc[m][n] = __builtin_amdgcn_mfma_f32_16x16x32_bf16(ahf, blf[n], acc[m][n], 0, 0, 0);
                    acc[m][n] = __builtin_amdgcn_mfma_f32_16x16x32_bf16(alf, bhf[n], acc[m][n], 0, 0, 0);
                }
            }
            __syncthreads();
        }

        // epilogue: lane holds D[code=(l4*4+r)+16m][xrow=l15+16n]
        const int cbase = kt * BN + wcode * 64 + l4 * 4;
        float c2v[4][4];
        #pragma unroll
        for (int m = 0; m < 4; ++m)
            #pragma unroll
            for (int r = 0; r < 4; ++r) c2v[m][r] = c2[cbase + m * 16 + r];

        if (PASS == 1) {
            #pragma unroll
            for (int n = 0; n < 4; ++n) {
                float dsv[4][4];
                float b1 = 1e30f, b2 = 1e30f; int i1 = 0;
                #pragma unroll
                for (int m = 0; m < 4; ++m)
                    #pragma unroll
                    for (int r = 0; r < 4; ++r) {
                        float d2 = fmaf(-2.f, acc[m][n][r], x2v[n] + c2v[m][r]);
                        float dv = sqrtf(fmaxf(d2, 0.f));
                        dsv[m][r] = dv;
                        bool better = dv < b1;
                        b2 = better ? b1 : fminf(b2, dv);
                        if (better) { b1 = dv; i1 = cbase + m * 16 + r; }
                    }
                float ls = 0.f, ts = 0.f;
                #pragma unroll
                for (int m = 0; m < 4; ++m)
                    #pragma unroll
                    for (int r = 0; r < 4; ++r) {
                        float e = __expf(b1 - dsv[m][r]);
                        ls += e;
                        ts = fmaf(e, b1 - dsv[m][r], ts);
                    }
                online_merge(rb1[n], ri1[n], rb2[n], rlv[n], rTv[n], b1, i1, b2, ls, ts);
            }
        } else {
            float ps[4][4];
            #pragma unroll
            for (int m = 0; m < 4; ++m)
                #pragma unroll
                for (int r = 0; r < 4; ++r) ps[m][r] = 0.f;
            #pragma unroll
            for (int n = 0; n < 4; ++n)
                #pragma unroll
                for (int m = 0; m < 4; ++m)
                    #pragma unroll
                    for (int r = 0; r < 4; ++r) {
                        float d2 = fmaf(-2.f, acc[m][n][r], x2v[n] + c2v[m][r]);
                        float dv = sqrtf(fmaxf(d2, 0.f));
                        ps[m][r] = fmaf(__expf(bdv[n] - dv), invl[n], ps[m][r]);
                    }
            #pragma unroll
            for (int m = 0; m < 4; ++m)
                #pragma unroll
                for (int r = 0; r < 4; ++r) {
                    float v = ps[m][r];
                    v += __shfl_xor(v, 1); v += __shfl_xor(v, 2);
                    v += __shfl_xor(v, 4); v += __shfl_xor(v, 8);
                    ps[m][r] = v;
                }
            if (l15 == 0) {
                #pragma unroll
                for (int m = 0; m < 4; ++m)
                    #pragma unroll
                    for (int r = 0; r < 4; ++r)
                        atomicAdd(&ws[WS_AVGP + cbase + m * 16 + r], ps[m][r]);
            }
        }
    }

    if (PASS == 1) {
        #pragma unroll
        for (int n = 0; n < 4; ++n) {
            #pragma unroll
            for (int off = 16; off <= 32; off <<= 1) {
                float ob1 = __shfl_xor(rb1[n], off);
                int   oi  = __shfl_xor(ri1[n], off);
                float ob2 = __shfl_xor(rb2[n], off);
                float ol  = __shfl_xor(rlv[n], off);
                float oT  = __shfl_xor(rTv[n], off);
                online_merge(rb1[n], ri1[n], rb2[n], rlv[n], rTv[n], ob1, oi, ob2, ol, oT);
            }
        }
        if (l4 == 0) {
            #pragma unroll
            for (int n = 0; n < 4; ++n) {
                int rl = wx * 64 + n * 16 + l15;
                sb1[rl][wcode] = rb1[n]; si1[rl][wcode] = ri1[n];
                sb2[rl][wcode] = rb2[n]; slv[rl][wcode] = rlv[n]; sTv[rl][wcode] = rTv[n];
            }
        }
        __syncthreads();
        if (tid < BM) {
            float b1 = sb1[tid][0]; int i1 = si1[tid][0];
            float b2 = sb2[tid][0]; float L = slv[tid][0]; float T = sTv[tid][0];
            #pragma unroll
            for (int s = 1; s < 4; ++s)
                online_merge(b1, i1, b2, L, T, sb1[tid][s], si1[tid][s], sb2[tid][s], slv[tid][s], sTv[tid][s]);
            int grow = blockRow + tid;
            ws[WS_BD + grow] = b1;
            ((int*)ws)[WS_BI + grow] = i1;
            ws[WS_L + grow] = L;
            if (b2 - b1 < TAU) {
                int p = atomicAdd(((int*)ws) + WS_FLAGN, 1);
                ((int*)ws)[WS_FLAGL + p] = grow;
            }
            float sval = T / L - __logf(L);
            #pragma unroll
            for (int off = 32; off >= 1; off >>= 1) sval += __shfl_xor(sval, off);
            if ((tid & 63) == 0) red[tid >> 6] = sval;
        }
        __syncthreads();
        if (tid == 0) atomicAdd(&ws[WS_SCAL + 1], red[0] + red[1]);
    }
}

__global__ void fixup_k(const float* __restrict__ x, const float* __restrict__ cb,
                        float* __restrict__ ws) {
    __shared__ float xr[DIM];
    __shared__ float rbd[256]; __shared__ int rbi[256];
    const int tid = threadIdx.x;
    const int nf = ((const int*)ws)[WS_FLAGN];
    for (int f = blockIdx.x; f < nf; f += gridDim.x) {
        int row = ((const int*)ws)[WS_FLAGL + f];
        __syncthreads();
        if (tid < 64) ((float4*)xr)[tid] = ((const float4*)(x + (size_t)row * DIM))[tid];
        __syncthreads();
        float x2r = ws[WS_X2 + row];
        float best = 1e30f; int bi = 0;
        for (int c = tid; c < KCODES; c += 256) {
            const float4* crow = (const float4*)(cb + (size_t)c * DIM);
            float dot = 0.f;
            for (int d4 = 0; d4 < 64; ++d4) {
                float4 cv = crow[d4]; float4 xv = ((const float4*)xr)[d4];
                dot = fmaf(cv.x, xv.x, dot); dot = fmaf(cv.y, xv.y, dot);
                dot = fmaf(cv.z, xv.z, dot); dot = fmaf(cv.w, xv.w, dot);
            }
            float d2 = fmaf(-2.f, dot, x2r + ws[WS_C2 + c]);
            float dv = sqrtf(fmaxf(d2, 0.f));
            if (dv < best) { best = dv; bi = c; }
        }
        rbd[tid] = best; rbi[tid] = bi;
        for (int s = 128; s > 0; s >>= 1) {
            __syncthreads();
            if (tid < s) {
                float ob = rbd[tid + s]; int oi = rbi[tid + s];
                if (ob < rbd[tid] || (ob == rbd[tid] && oi < rbi[tid])) { rbd[tid] = ob; rbi[tid] = oi; }
            }
        }
        __syncthreads();
        if (tid == 0) ((int*)ws)[WS_BI + row] = rbi[0];
    }
}

__global__ void gather_k(const float* __restrict__ x, const float* __restrict__ cb,
                         float* __restrict__ ws, float* __restrict__ outQ,
                         float* __restrict__ outNcbe, float* __restrict__ outIdxF) {
    __shared__ float red2[4];
    const int tid = threadIdx.x, w = tid >> 6, lane = tid & 63;
    float msum = 0.f;
    for (int it = 0; it < 8; ++it) {
        int n = blockIdx.x * 32 + it * 4 + w;
        int idx = ((const int*)ws)[WS_BI + n];
        float4 xv = ((const float4*)(x + (size_t)n * DIM))[lane];
        float4 cv = ((const float4*)(cb + (size_t)idx * DIM))[lane];
        ((float4*)(outQ + (size_t)n * DIM))[lane] = cv;   // x + (q - x) == q
        float* dst = outNcbe + (size_t)idx * DIM + lane * 4;
        const float g = 0.01f;
        atomicAdd(dst + 0, g * xv.x); atomicAdd(dst + 1, g * xv.y);
        atomicAdd(dst + 2, g * xv.z); atomicAdd(dst + 3, g * xv.w);
        float dx = cv.x - xv.x, dy = cv.y - xv.y, dz = cv.z - xv.z, dw = cv.w - xv.w;
        float s = dx*dx + dy*dy + dz*dz + dw*dw;
        #pragma unroll
        for (int off = 32; off >= 1; off >>= 1) s += __shfl_xor(s, off);
        if (lane == 0) {
            msum += s;
            atomicAdd(&ws[WS_CNT + idx], 1.0f);
            outIdxF[n] = (float)idx;
        }
    }
    if (lane == 0) red2[w] = msum;
    __syncthreads();
    if (tid == 0) atomicAdd(&ws[WS_SCAL + 0], red2[0] + red2[1] + red2[2] + red2[3]);
}

__global__ void stats_k(const float* __restrict__ cse, float* __restrict__ ws,
                        float* __restrict__ outNcse) {
    int tid = threadIdx.x, lane = tid & 63;
    int k = blockIdx.x * 256 + tid;
    float cnt = ws[WS_CNT + k];
    float ncse = 0.99f * cse[k] + 0.01f * cnt;
    outNcse[k] = ncse;
    float ap  = ws[WS_AVGP + k] * (1.0f / N_ROWS);
    float ae  = -(ap * __logf(ap + 1e-5f));
    float app = cnt * (1.0f / N_ROWS);
    float pe  = -(app * __logf(app + 1e-10f));
    #pragma unroll
    for (int off = 32; off >= 1; off >>= 1) {
        ncse += __shfl_xor(ncse, off);
        ae   += __shfl_xor(ae, off);
        pe   += __shfl_xor(pe, off);
    }
    if (lane == 0) {
        atomicAdd(&ws[WS_SCAL + 4], ncse);
        atomicAdd(&ws[WS_SCAL + 2], ae);
        atomicAdd(&ws[WS_SCAL + 3], pe);
    }
}

__global__ void newcb_k(const float* __restrict__ ws, const float* __restrict__ outNcse,
                        const float* __restrict__ outNcbe, float* __restrict__ outNc) {
    int w = threadIdx.x >> 6, lane = threadIdx.x & 63;
    int k = blockIdx.x * 4 + w;
    float n = ws[WS_SCAL + 4];
    float ncse = outNcse[k];
    float smoothed = (ncse + 1e-5f) / (n + (float)KCODES * 1e-5f) * n;
    float inv = 1.0f / smoothed;
    float4 v = ((const float4*)(outNcbe + (size_t)k * DIM))[lane];
    v.x *= inv; v.y *= inv; v.z *= inv; v.w *= inv;
    ((float4*)(outNc + (size_t)k * DIM))[lane] = v;
}

__global__ void finalize_k(const float* __restrict__ ws, float* __restrict__ outLoss,
                           float* __restrict__ outPerp) {
    float mse  = ws[WS_SCAL + 0] * (1.0f / ((float)N_ROWS * 256.0f));
    float sent = -ws[WS_SCAL + 1] * (1.0f / (float)N_ROWS);
    float ent  = sent - ws[WS_SCAL + 2];
    outLoss[0] = 1.25f * mse + 0.1f * ent;
    outPerp[0] = expf(ws[WS_SCAL + 3]);
}

extern "C" void kernel_launch(void* const* d_in, const int* in_sizes, int n_in,
                              void* d_out, int out_size, void* d_ws, size_t ws_size,
                              hipStream_t stream) {
    const float* x   = (const float*)d_in[0];
    const float* cb  = (const float*)d_in[1];
    const float* cse = (const float*)d_in[2];
    const float* cbe = (const float*)d_in[3];
    float* out = (float*)d_out;
    float* ws  = (float*)d_ws;

    float* outQ    = out;
    float* outLoss = out + 8388608;
    float* outPerp = out + 8388609;
    float* outIdxF = out + 8388610;
    float* outNc   = out + 8421378;
    float* outNcse = out + 10518530;
    float* outNcbe = out + 10526722;

    // scratch inside d_out (rewritten later): x splits in outQ, cb splits in outNc(+2 for 16B align)
    ushort* xh = (ushort*)outQ;
    ushort* xl = xh + (size_t)N_ROWS * DIM;
    ushort* ch = (ushort*)(out + 8421380);
    ushort* cl = ch + (size_t)KCODES * DIM;

    hipMemsetAsync(ws + WS_AVGP, 0, (size_t)(WS_FLAGN + 1 - WS_AVGP) * sizeof(float), stream);
    rownorm_k<<<KCODES / 4, 256, 0, stream>>>(cb, ws + WS_C2, KCODES);
    rownorm_k<<<N_ROWS / 4, 256, 0, stream>>>(x, ws + WS_X2, N_ROWS);
    split_k<<<N_ROWS * DIM / 8 / 256, 256, 0, stream>>>(x, xh, xl);
    split_k<<<KCODES * DIM / 8 / 256, 256, 0, stream>>>(cb, ch, cl);
    vq_mfma<1><<<N_ROWS / BM, 512, 0, stream>>>(xh, xl, ch, cl, ws);
    vq_mfma<2><<<N_ROWS / BM, 512, 0, stream>>>(xh, xl, ch, cl, ws);
    fixup_k<<<64, 256, 0, stream>>>(x, cb, ws);
    init_ncbe_k<<<2048, 256, 0, stream>>>(cbe, outNcbe);
    gather_k<<<1024, 256, 0, stream>>>(x, cb, ws, outQ, outNcbe, outIdxF);
    stats_k<<<KCODES / 256, 256, 0, stream>>>(cse, ws, outNcse);
    newcb_k<<<KCODES / 4, 256, 0, stream>>>(ws, outNcse, outNcbe, outNc);
    finalize_k<<<1, 1, 0, stream>>>(ws, outLoss, outPerp);
}

// Round 4
// 2381.776 us; speedup vs baseline: 2.5656x; 1.1392x over previous
//
#include <hip/hip_runtime.h>
#include <math.h>

#define N_ROWS 32768
#define DIM 256
#define KCODES 8192

#define BM 128
#define BN 256
#define NSLICE 8
#define SLICE_K 1024          // codes per XCD slice
#define CHUNK_R 1024          // rows per block
#define NRT (CHUNK_R / BM)    // 8 row-tiles per block
#define NKT (SLICE_K / BN)    // 4 code-tiles per slice
#define NDT 8                 // 256 dims / 32
#define NSTEP (NRT * NKT * NDT)  // 256
#define TAU 1e-3f

// ws layout (float offsets)
#define WS_C2    0
#define WS_X2    8192
#define WS_BD    40960
#define WS_BI    73728
#define WS_L     106496
#define WS_FLAGL 139264
#define WS_AVGP  172032
#define WS_CNT   180224
#define WS_SCAL  188416      // 0=mse 1=sum p*logp 2=avg_entropy 3=pent 4=nsum
#define WS_FLAGN 188424

#define PF (NSLICE * N_ROWS)  // partial field stride = 262144

typedef __bf16 bf16x8 __attribute__((ext_vector_type(8)));
typedef float  f32x4  __attribute__((ext_vector_type(4)));

__device__ __forceinline__ void gll16(const void* g, void* l) {
    __builtin_amdgcn_global_load_lds((const __attribute__((address_space(1))) void*)g,
                                     (__attribute__((address_space(3))) void*)l, 16, 0, 0);
}

__global__ void rownorm_k(const float* __restrict__ A, float* __restrict__ out, int rows) {
    int w = threadIdx.x >> 6, lane = threadIdx.x & 63;
    int r = blockIdx.x * 4 + w;
    if (r >= rows) return;
    const float4* A4 = (const float4*)(A + (size_t)r * DIM);
    float4 v = A4[lane];
    float s = v.x*v.x + v.y*v.y + v.z*v.z + v.w*v.w;
    #pragma unroll
    for (int off = 32; off >= 1; off >>= 1) s += __shfl_xor(s, off);
    if (lane == 0) out[r] = s;
}

__global__ void split_k(const float* __restrict__ src, ushort* __restrict__ h,
                        ushort* __restrict__ l) {
    int i = blockIdx.x * 256 + threadIdx.x;
    const float4* s4 = (const float4*)src;
    float4 v0 = s4[2 * i], v1 = s4[2 * i + 1];
    float vv[8] = {v0.x, v0.y, v0.z, v0.w, v1.x, v1.y, v1.z, v1.w};
    uint hw[4], lw[4];
    #pragma unroll
    for (int p = 0; p < 4; ++p) {
        uint ua = __float_as_uint(vv[2*p]), ub = __float_as_uint(vv[2*p+1]);
        uint ha = ua & 0xFFFF0000u, hb = ub & 0xFFFF0000u;
        float ra = vv[2*p]     - __uint_as_float(ha);
        float rb = vv[2*p + 1] - __uint_as_float(hb);
        hw[p] = hb | (ha >> 16);
        lw[p] = (__float_as_uint(rb) & 0xFFFF0000u) | (__float_as_uint(ra) >> 16);
    }
    ((uint4*)h)[i] = make_uint4(hw[0], hw[1], hw[2], hw[3]);
    ((uint4*)l)[i] = make_uint4(lw[0], lw[1], lw[2], lw[3]);
}

__global__ void init_ncbe_k(const float* __restrict__ cbe, float* __restrict__ outNcbe) {
    int i = blockIdx.x * 256 + threadIdx.x;
    float4 v = ((const float4*)cbe)[i];
    v.x *= 0.99f; v.y *= 0.99f; v.z *= 0.99f; v.w *= 0.99f;
    ((float4*)outNcbe)[i] = v;
}

__device__ __forceinline__ void online_merge(float& b1, int& i1, float& b2, float& l, float& T,
                                             float nb1, int ni1, float nb2, float nl, float nT) {
    float m  = fminf(b1, nb1);
    float fa = __expf(m - b1);
    float fb = __expf(m - nb1);
    float L  = fa * l + fb * nl;
    float TT = fa * (T + (m - b1) * l) + fb * (nT + (m - nb1) * nl);
    float losing = fmaxf(b1, nb1);
    float B2 = fminf(fminf(b2, nb2), losing);
    if (nb1 < b1 || (nb1 == b1 && ni1 < i1)) i1 = ni1;
    b1 = m; b2 = B2; l = L; T = TT;
}

// stage step t: cbh[256][32] | cbl | xh[128][32] | xl  (pre-swizzled source)
__device__ __forceinline__ void stage(int t, ushort* buf,
                                      const ushort* __restrict__ xh, const ushort* __restrict__ xl,
                                      const ushort* __restrict__ ch, const ushort* __restrict__ cl,
                                      int slice, int chunk, int wid, int lane) {
    const int rt = t >> 5, kt = (t >> 3) & 3, dt = t & 7;
    const int rsub = lane >> 2, s = lane & 3;
    #pragma unroll
    for (int i = 0; i < 6; ++i) {
        const int c = wid * 6 + i;
        if (c < 32) {
            const int half = c >> 4;
            const int cc = c & 15;
            const int row = cc * 16 + rsub;
            const int col = s ^ ((rsub >> 2) & 3);
            const int g = slice * SLICE_K + kt * BN + row;
            const ushort* src = (half ? cl : ch) + (((size_t)g) << 8) + (dt << 5) + (col << 3);
            ushort* dst = buf + (half << 13) + (cc << 9);
            gll16(src, dst);
        } else {
            const int half = (c >> 3) & 1;
            const int cc = c & 7;
            const int row = cc * 16 + rsub;
            const int col = s ^ ((rsub >> 2) & 3);
            const int g = chunk * CHUNK_R + rt * BM + row;
            const ushort* src = (half ? xl : xh) + (((size_t)g) << 8) + (dt << 5) + (col << 3);
            ushort* dst = buf + 16384 + (half << 12) + (cc << 9);
            gll16(src, dst);
        }
    }
}

// PASS 1: per-slice argmin (+2nd) + online softmax partials.  PASS 2: avg_probs for own slice.
template<int PASS>
__global__ __launch_bounds__(512) void vq_mfma(const ushort* __restrict__ xh,
                                               const ushort* __restrict__ xl,
                                               const ushort* __restrict__ ch,
                                               const ushort* __restrict__ cl,
                                               float* __restrict__ ws,
                                               float* __restrict__ P) {
    __shared__ __align__(16) ushort lds[2][24576];   // 96 KB
    __shared__ float sb1[BM][4]; __shared__ int si1[BM][4];
    __shared__ float sb2[BM][4]; __shared__ float slv[BM][4]; __shared__ float sTv[BM][4];

    const int tid  = threadIdx.x;
    const int lane = tid & 63, wid = tid >> 6;
    const int wcode = wid & 3, wx = wid >> 2;
    const int l15 = lane & 15, l4 = lane >> 4;
    const int slice = blockIdx.x & 7, chunk = blockIdx.x >> 3;
    const int fsw = ((l4 ^ (l15 >> 2)) << 3);

    const float* c2  = ws + WS_C2;
    const float* x2p = ws + WS_X2;

    stage(0, lds[0], xh, xl, ch, cl, slice, chunk, wid, lane);
    __syncthreads();

    for (int rt = 0; rt < NRT; ++rt) {
        const int rowBase = chunk * CHUNK_R + rt * BM;
        float x2v[4], bdv[4], invl[4];
        #pragma unroll
        for (int n = 0; n < 4; ++n) {
            int rl = wx * 64 + n * 16 + l15;
            x2v[n] = x2p[rowBase + rl];
            if (PASS == 2) {
                bdv[n]  = ws[WS_BD + rowBase + rl];
                invl[n] = 1.0f / ws[WS_L + rowBase + rl];
            }
        }
        float rb1[4], rb2[4], rlv[4], rTv[4]; int ri1[4];
        #pragma unroll
        for (int n = 0; n < 4; ++n) { rb1[n] = 1e30f; rb2[n] = 1e30f; rlv[n] = 0.f; rTv[n] = 0.f; ri1[n] = 0; }

        for (int kt = 0; kt < NKT; ++kt) {
            f32x4 acc[4][4];
            #pragma unroll
            for (int m = 0; m < 4; ++m)
                #pragma unroll
                for (int n = 0; n < 4; ++n) acc[m][n] = (f32x4){0.f, 0.f, 0.f, 0.f};

            #pragma unroll
            for (int dt = 0; dt < NDT; ++dt) {
                const int t = rt * 32 + kt * 8 + dt;
                if (t + 1 < NSTEP)
                    stage(t + 1, lds[(t + 1) & 1], xh, xl, ch, cl, slice, chunk, wid, lane);

                const ushort* bb = lds[t & 1];
                bf16x8 bhf[4], blf[4];
                #pragma unroll
                for (int n = 0; n < 4; ++n) {
                    int off = (wx * 64 + n * 16 + l15) * 32 + fsw;
                    bhf[n] = __builtin_bit_cast(bf16x8, *(const uint4*)(bb + 16384 + off));
                    blf[n] = __builtin_bit_cast(bf16x8, *(const uint4*)(bb + 20480 + off));
                }
                #pragma unroll
                for (int m = 0; m < 4; ++m) {
                    int off = (wcode * 64 + m * 16 + l15) * 32 + fsw;
                    bf16x8 ahf = __builtin_bit_cast(bf16x8, *(const uint4*)(bb + off));
                    bf16x8 alf = __builtin_bit_cast(bf16x8, *(const uint4*)(bb + 8192 + off));
                    #pragma unroll
                    for (int n = 0; n < 4; ++n) {
                        acc[m][n] = __builtin_amdgcn_mfma_f32_16x16x32_bf16(ahf, bhf[n], acc[m][n], 0, 0, 0);
                        acc[m][n] = __builtin_amdgcn_mfma_f32_16x16x32_bf16(ahf, blf[n], acc[m][n], 0, 0, 0);
                        acc[m][n] = __builtin_amdgcn_mfma_f32_16x16x32_bf16(alf, bhf[n], acc[m][n], 0, 0, 0);
                    }
                }
                __syncthreads();
            }

            // epilogue: lane holds D[code=(l4*4+r)+16m (tile)][xrow=l15+16n]
            const int cbase = slice * SLICE_K + kt * BN + wcode * 64 + l4 * 4;
            float c2v[4][4];
            #pragma unroll
            for (int m = 0; m < 4; ++m)
                #pragma unroll
                for (int r = 0; r < 4; ++r) c2v[m][r] = c2[cbase + m * 16 + r];

            if (PASS == 1) {
                #pragma unroll
                for (int n = 0; n < 4; ++n) {
                    float dsv[4][4];
                    float b1 = 1e30f, b2 = 1e30f; int i1 = 0;
                    #pragma unroll
                    for (int m = 0; m < 4; ++m)
                        #pragma unroll
                        for (int r = 0; r < 4; ++r) {
                            float d2 = fmaf(-2.f, acc[m][n][r], x2v[n] + c2v[m][r]);
                            float dv = sqrtf(fmaxf(d2, 0.f));
                            dsv[m][r] = dv;
                            bool better = dv < b1;
                            b2 = better ? b1 : fminf(b2, dv);
                            if (better) { b1 = dv; i1 = cbase + m * 16 + r; }
                        }
                    float ls = 0.f, ts = 0.f;
                    #pragma unroll
                    for (int m = 0; m < 4; ++m)
                        #pragma unroll
                        for (int r = 0; r < 4; ++r) {
                            float e = __expf(b1 - dsv[m][r]);
                            ls += e;
                            ts = fmaf(e, b1 - dsv[m][r], ts);
                        }
                    online_merge(rb1[n], ri1[n], rb2[n], rlv[n], rTv[n], b1, i1, b2, ls, ts);
                }
            } else {
                float ps[4][4];
                #pragma unroll
                for (int m = 0; m < 4; ++m)
                    #pragma unroll
                    for (int r = 0; r < 4; ++r) ps[m][r] = 0.f;
                #pragma unroll
                for (int n = 0; n < 4; ++n)
                    #pragma unroll
                    for (int m = 0; m < 4; ++m)
                        #pragma unroll
                        for (int r = 0; r < 4; ++r) {
                            float d2 = fmaf(-2.f, acc[m][n][r], x2v[n] + c2v[m][r]);
                            float dv = sqrtf(fmaxf(d2, 0.f));
                            ps[m][r] = fmaf(__expf(bdv[n] - dv), invl[n], ps[m][r]);
                        }
                #pragma unroll
                for (int m = 0; m < 4; ++m)
                    #pragma unroll
                    for (int r = 0; r < 4; ++r) {
                        float v = ps[m][r];
                        v += __shfl_xor(v, 1); v += __shfl_xor(v, 2);
                        v += __shfl_xor(v, 4); v += __shfl_xor(v, 8);
                        ps[m][r] = v;
                    }
                if (l15 == 0) {
                    #pragma unroll
                    for (int m = 0; m < 4; ++m)
                        #pragma unroll
                        for (int r = 0; r < 4; ++r)
                            atomicAdd(&ws[WS_AVGP + cbase + m * 16 + r], ps[m][r]);
                }
            }
        }

        if (PASS == 1) {
            #pragma unroll
            for (int n = 0; n < 4; ++n) {
                #pragma unroll
                for (int off = 16; off <= 32; off <<= 1) {
                    float ob1 = __shfl_xor(rb1[n], off);
                    int   oi  = __shfl_xor(ri1[n], off);
                    float ob2 = __shfl_xor(rb2[n], off);
                    float ol  = __shfl_xor(rlv[n], off);
                    float oT  = __shfl_xor(rTv[n], off);
                    online_merge(rb1[n], ri1[n], rb2[n], rlv[n], rTv[n], ob1, oi, ob2, ol, oT);
                }
            }
            if (l4 == 0) {
                #pragma unroll
                for (int n = 0; n < 4; ++n) {
                    int rl = wx * 64 + n * 16 + l15;
                    sb1[rl][wcode] = rb1[n]; si1[rl][wcode] = ri1[n];
                    sb2[rl][wcode] = rb2[n]; slv[rl][wcode] = rlv[n]; sTv[rl][wcode] = rTv[n];
                }
            }
            __syncthreads();
            if (tid < BM) {
                float b1 = sb1[tid][0]; int i1 = si1[tid][0];
                float b2 = sb2[tid][0]; float L = slv[tid][0]; float T = sTv[tid][0];
                #pragma unroll
                for (int s = 1; s < 4; ++s)
                    online_merge(b1, i1, b2, L, T, sb1[tid][s], si1[tid][s], sb2[tid][s], slv[tid][s], sTv[tid][s]);
                int grow = rowBase + tid;
                P[0 * PF + slice * N_ROWS + grow] = b1;
                P[1 * PF + slice * N_ROWS + grow] = b2;
                P[2 * PF + slice * N_ROWS + grow] = L;
                P[3 * PF + slice * N_ROWS + grow] = T;
                ((int*)P)[4 * PF + slice * N_ROWS + grow] = i1;
            }
            __syncthreads();
        }
    }
}

// merge 8 slice-partials per row -> final stats + flags + entropy sum
__global__ void merge_k(const float* __restrict__ P, float* __restrict__ ws) {
    const int tid = threadIdx.x, lane = tid & 63;
    const int row = blockIdx.x * 256 + tid;
    float b1 = 1e30f, b2 = 1e30f, L = 0.f, T = 0.f; int i1 = 0;
    #pragma unroll
    for (int s = 0; s < NSLICE; ++s) {
        float nb1 = P[0 * PF + s * N_ROWS + row];
        float nb2 = P[1 * PF + s * N_ROWS + row];
        float nl  = P[2 * PF + s * N_ROWS + row];
        float nT  = P[3 * PF + s * N_ROWS + row];
        int   ni  = ((const int*)P)[4 * PF + s * N_ROWS + row];
        online_merge(b1, i1, b2, L, T, nb1, ni, nb2, nl, nT);
    }
    ws[WS_BD + row] = b1;
    ((int*)ws)[WS_BI + row] = i1;
    ws[WS_L + row] = L;
    if (b2 - b1 < TAU) {
        int p = atomicAdd(((int*)ws) + WS_FLAGN, 1);
        ((int*)ws)[WS_FLAGL + p] = row;
    }
    float sval = T / L - __logf(L);
    #pragma unroll
    for (int off = 32; off >= 1; off >>= 1) sval += __shfl_xor(sval, off);
    if (lane == 0) atomicAdd(&ws[WS_SCAL + 1], sval);
}

__global__ void fixup_k(const float* __restrict__ x, const float* __restrict__ cb,
                        float* __restrict__ ws) {
    __shared__ float xr[DIM];
    __shared__ float rbd[256]; __shared__ int rbi[256];
    const int tid = threadIdx.x;
    const int nf = ((const int*)ws)[WS_FLAGN];
    for (int f = blockIdx.x; f < nf; f += gridDim.x) {
        int row = ((const int*)ws)[WS_FLAGL + f];
        __syncthreads();
        if (tid < 64) ((float4*)xr)[tid] = ((const float4*)(x + (size_t)row * DIM))[tid];
        __syncthreads();
        float x2r = ws[WS_X2 + row];
        float best = 1e30f; int bi = 0;
        for (int c = tid; c < KCODES; c += 256) {
            const float4* crow = (const float4*)(cb + (size_t)c * DIM);
            float dot = 0.f;
            for (int d4 = 0; d4 < 64; ++d4) {
                float4 cv = crow[d4]; float4 xv = ((const float4*)xr)[d4];
                dot = fmaf(cv.x, xv.x, dot); dot = fmaf(cv.y, xv.y, dot);
                dot = fmaf(cv.z, xv.z, dot); dot = fmaf(cv.w, xv.w, dot);
            }
            float d2 = fmaf(-2.f, dot, x2r + ws[WS_C2 + c]);
            float dv = sqrtf(fmaxf(d2, 0.f));
            if (dv < best) { best = dv; bi = c; }
        }
        rbd[tid] = best; rbi[tid] = bi;
        for (int s = 128; s > 0; s >>= 1) {
            __syncthreads();
            if (tid < s) {
                float ob = rbd[tid + s]; int oi = rbi[tid + s];
                if (ob < rbd[tid] || (ob == rbd[tid] && oi < rbi[tid])) { rbd[tid] = ob; rbi[tid] = oi; }
            }
        }
        __syncthreads();
        if (tid == 0) ((int*)ws)[WS_BI + row] = rbi[0];
    }
}

__global__ void gather_k(const float* __restrict__ x, const float* __restrict__ cb,
                         float* __restrict__ ws, float* __restrict__ outQ,
                         float* __restrict__ outNcbe, float* __restrict__ outIdxF) {
    __shared__ float red2[4];
    const int tid = threadIdx.x, w = tid >> 6, lane = tid & 63;
    float msum = 0.f;
    for (int it = 0; it < 8; ++it) {
        int n = blockIdx.x * 32 + it * 4 + w;
        int idx = ((const int*)ws)[WS_BI + n];
        float4 xv = ((const float4*)(x + (size_t)n * DIM))[lane];
        float4 cv = ((const float4*)(cb + (size_t)idx * DIM))[lane];
        ((float4*)(outQ + (size_t)n * DIM))[lane] = cv;
        float* dst = outNcbe + (size_t)idx * DIM + lane * 4;
        const float g = 0.01f;
        atomicAdd(dst + 0, g * xv.x); atomicAdd(dst + 1, g * xv.y);
        atomicAdd(dst + 2, g * xv.z); atomicAdd(dst + 3, g * xv.w);
        float dx = cv.x - xv.x, dy = cv.y - xv.y, dz = cv.z - xv.z, dw = cv.w - xv.w;
        float s = dx*dx + dy*dy + dz*dz + dw*dw;
        #pragma unroll
        for (int off = 32; off >= 1; off >>= 1) s += __shfl_xor(s, off);
        if (lane == 0) {
            msum += s;
            atomicAdd(&ws[WS_CNT + idx], 1.0f);
            outIdxF[n] = (float)idx;
        }
    }
    if (lane == 0) red2[w] = msum;
    __syncthreads();
    if (tid == 0) atomicAdd(&ws[WS_SCAL + 0], red2[0] + red2[1] + red2[2] + red2[3]);
}

__global__ void stats_k(const float* __restrict__ cse, float* __restrict__ ws,
                        float* __restrict__ outNcse) {
    int tid = threadIdx.x, lane = tid & 63;
    int k = blockIdx.x * 256 + tid;
    float cnt = ws[WS_CNT + k];
    float ncse = 0.99f * cse[k] + 0.01f * cnt;
    outNcse[k] = ncse;
    float ap  = ws[WS_AVGP + k] * (1.0f / N_ROWS);
    float ae  = -(ap * __logf(ap + 1e-5f));
    float app = cnt * (1.0f / N_ROWS);
    float pe  = -(app * __logf(app + 1e-10f));
    #pragma unroll
    for (int off = 32; off >= 1; off >>= 1) {
        ncse += __shfl_xor(ncse, off);
        ae   += __shfl_xor(ae, off);
        pe   += __shfl_xor(pe, off);
    }
    if (lane == 0) {
        atomicAdd(&ws[WS_SCAL + 4], ncse);
        atomicAdd(&ws[WS_SCAL + 2], ae);
        atomicAdd(&ws[WS_SCAL + 3], pe);
    }
}

__global__ void newcb_k(const float* __restrict__ ws, const float* __restrict__ outNcse,
                        const float* __restrict__ outNcbe, float* __restrict__ outNc) {
    int w = threadIdx.x >> 6, lane = threadIdx.x & 63;
    int k = blockIdx.x * 4 + w;
    float n = ws[WS_SCAL + 4];
    float ncse = outNcse[k];
    float smoothed = (ncse + 1e-5f) / (n + (float)KCODES * 1e-5f) * n;
    float inv = 1.0f / smoothed;
    float4 v = ((const float4*)(outNcbe + (size_t)k * DIM))[lane];
    v.x *= inv; v.y *= inv; v.z *= inv; v.w *= inv;
    ((float4*)(outNc + (size_t)k * DIM))[lane] = v;
}

__global__ void finalize_k(const float* __restrict__ ws, float* __restrict__ outLoss,
                           float* __restrict__ outPerp) {
    float mse  = ws[WS_SCAL + 0] * (1.0f / ((float)N_ROWS * 256.0f));
    float sent = -ws[WS_SCAL + 1] * (1.0f / (float)N_ROWS);
    float ent  = sent - ws[WS_SCAL + 2];
    outLoss[0] = 1.25f * mse + 0.1f * ent;
    outPerp[0] = expf(ws[WS_SCAL + 3]);
}

extern "C" void kernel_launch(void* const* d_in, const int* in_sizes, int n_in,
                              void* d_out, int out_size, void* d_ws, size_t ws_size,
                              hipStream_t stream) {
    const float* x   = (const float*)d_in[0];
    const float* cb  = (const float*)d_in[1];
    const float* cse = (const float*)d_in[2];
    const float* cbe = (const float*)d_in[3];
    float* out = (float*)d_out;
    float* ws  = (float*)d_ws;

    float* outQ    = out;
    float* outLoss = out + 8388608;
    float* outPerp = out + 8388609;
    float* outIdxF = out + 8388610;
    float* outNc   = out + 8421378;
    float* outNcse = out + 10518530;
    float* outNcbe = out + 10526722;

    // scratch inside d_out: x splits in outQ, cb splits in outNc(+2 align), partials in outNcbe
    ushort* xh = (ushort*)outQ;
    ushort* xl = xh + (size_t)N_ROWS * DIM;
    ushort* ch = (ushort*)(out + 8421380);
    ushort* cl = ch + (size_t)KCODES * DIM;
    float*  P  = outNcbe;   // 5*PF floats = 5.24 MB <= 8.39 MB

    hipMemsetAsync(ws + WS_AVGP, 0, (size_t)(WS_FLAGN + 1 - WS_AVGP) * sizeof(float), stream);
    rownorm_k<<<KCODES / 4, 256, 0, stream>>>(cb, ws + WS_C2, KCODES);
    rownorm_k<<<N_ROWS / 4, 256, 0, stream>>>(x, ws + WS_X2, N_ROWS);
    split_k<<<N_ROWS * DIM / 8 / 256, 256, 0, stream>>>(x, xh, xl);
    split_k<<<KCODES * DIM / 8 / 256, 256, 0, stream>>>(cb, ch, cl);
    vq_mfma<1><<<256, 512, 0, stream>>>(xh, xl, ch, cl, ws, P);
    merge_k<<<N_ROWS / 256, 256, 0, stream>>>(P, ws);
    vq_mfma<2><<<256, 512, 0, stream>>>(xh, xl, ch, cl, ws, P);
    fixup_k<<<64, 256, 0, stream>>>(x, cb, ws);
    init_ncbe_k<<<2048, 256, 0, stream>>>(cbe, outNcbe);
    gather_k<<<1024, 256, 0, stream>>>(x, cb, ws, outQ, outNcbe, outIdxF);
    stats_k<<<KCODES / 256, 256, 0, stream>>>(cse, ws, outNcse);
    newcb_k<<<KCODES / 4, 256, 0, stream>>>(ws, outNcse, outNcbe, outNc);
    finalize_k<<<1, 1, 0, stream>>>(ws, outLoss, outPerp);
}

// Round 6
// 1460.196 us; speedup vs baseline: 4.1848x; 1.6311x over previous
//
#include <hip/hip_runtime.h>
#include <math.h>

#define N_ROWS 32768
#define DIM 256
#define KCODES 8192

#define BM 128
#define BN 128
#define NSLICE 8
#define SLICE_K 1024
#define CHUNK_R 512
#define NRT (CHUNK_R / BM)        // 4
#define NKT (SLICE_K / BN)        // 8
#define NDT 8
#define NSTEP (NRT * NKT * NDT)   // 256
#define TAU 3e-4f

#define FAST_SQRT(x) __builtin_amdgcn_sqrtf(x)

// ws layout (float offsets)
#define WS_C2    0
#define WS_X2    8192
#define WS_BD    40960
#define WS_BI    73728
#define WS_L     106496
#define WS_FLAGL 139264
#define WS_AVGP  172032
#define WS_CNT   180224
#define WS_SCAL  188416      // 0=mse 1=sum p*logp 2=avg_entropy 3=pent 4=nsum
#define WS_FLAGN 188424

#define PF (NSLICE * N_ROWS)

typedef __bf16 bf16x8 __attribute__((ext_vector_type(8)));
typedef float  f32x4  __attribute__((ext_vector_type(4)));

__device__ __forceinline__ void gll16(const void* g, void* l) {
    __builtin_amdgcn_global_load_lds((const __attribute__((address_space(1))) void*)g,
                                     (__attribute__((address_space(3))) void*)l, 16, 0, 0);
}

__global__ void rownorm_k(const float* __restrict__ A, float* __restrict__ out, int rows) {
    int w = threadIdx.x >> 6, lane = threadIdx.x & 63;
    int r = blockIdx.x * 4 + w;
    if (r >= rows) return;
    const float4* A4 = (const float4*)(A + (size_t)r * DIM);
    float4 v = A4[lane];
    float s = v.x*v.x + v.y*v.y + v.z*v.z + v.w*v.w;
    #pragma unroll
    for (int off = 32; off >= 1; off >>= 1) s += __shfl_xor(s, off);
    if (lane == 0) out[r] = s;
}

__global__ void split_k(const float* __restrict__ src, ushort* __restrict__ h,
                        ushort* __restrict__ l) {
    int i = blockIdx.x * 256 + threadIdx.x;
    const float4* s4 = (const float4*)src;
    float4 v0 = s4[2 * i], v1 = s4[2 * i + 1];
    float vv[8] = {v0.x, v0.y, v0.z, v0.w, v1.x, v1.y, v1.z, v1.w};
    uint hw[4], lw[4];
    #pragma unroll
    for (int p = 0; p < 4; ++p) {
        uint ua = __float_as_uint(vv[2*p]), ub = __float_as_uint(vv[2*p+1]);
        uint ha = ua & 0xFFFF0000u, hb = ub & 0xFFFF0000u;
        float ra = vv[2*p]     - __uint_as_float(ha);
        float rb = vv[2*p + 1] - __uint_as_float(hb);
        hw[p] = hb | (ha >> 16);
        lw[p] = (__float_as_uint(rb) & 0xFFFF0000u) | (__float_as_uint(ra) >> 16);
    }
    ((uint4*)h)[i] = make_uint4(hw[0], hw[1], hw[2], hw[3]);
    ((uint4*)l)[i] = make_uint4(lw[0], lw[1], lw[2], lw[3]);
}

__global__ void init_ncbe_k(const float* __restrict__ cbe, float* __restrict__ outNcbe) {
    int i = blockIdx.x * 256 + threadIdx.x;
    float4 v = ((const float4*)cbe)[i];
    v.x *= 0.99f; v.y *= 0.99f; v.z *= 0.99f; v.w *= 0.99f;
    ((float4*)outNcbe)[i] = v;
}

__device__ __forceinline__ void online_merge(float& b1, int& i1, float& b2, float& l, float& T,
                                             float nb1, int ni1, float nb2, float nl, float nT) {
    float m  = fminf(b1, nb1);
    float fa = __expf(m - b1);
    float fb = __expf(m - nb1);
    float L  = fa * l + fb * nl;
    float TT = fa * (T + (m - b1) * l) + fb * (nT + (m - nb1) * nl);
    float losing = fmaxf(b1, nb1);
    float B2 = fminf(fminf(b2, nb2), losing);
    if (nb1 < b1 || (nb1 == b1 && ni1 < i1)) i1 = ni1;
    b1 = m; b2 = B2; l = L; T = TT;
}

// regions per 16KB buffer (ushorts): cbh[0) cbl[4096) xh[8192) xl[12288)
__device__ __forceinline__ void do_stage(int t, ushort* lds0,
                                         const ushort* const (&sbase)[4],
                                         const int (&sdst)[4], const bool (&siscb)[4]) {
    const int cbo = (((t >> 3) & 7) << 15) | ((t & 7) << 5);   // kt*BN*256 + dt*32
    const int xo  = ((t >> 6) << 15) | ((t & 7) << 5);         // rt*BM*256 + dt*32
    ushort* lb = lds0 + ((t & 1) << 14);
    #pragma unroll
    for (int i = 0; i < 4; ++i)
        gll16(sbase[i] + (siscb[i] ? cbo : xo), lb + sdst[i]);
}

// PASS 1: per-slice argmin (+2nd) + online softmax partials.  PASS 2: avg_probs for own slice.
template<int PASS>
__global__ __launch_bounds__(512, 4) void vq_mfma(const ushort* __restrict__ xh,
                                                  const ushort* __restrict__ xl,
                                                  const ushort* __restrict__ ch,
                                                  const ushort* __restrict__ cl,
                                                  float* __restrict__ ws,
                                                  float* __restrict__ P) {
    __shared__ __align__(16) ushort lds[2][16384];   // 64 KB double buffer
    __shared__ float sred[1536];  // P1: b1|b2|l|T [256 each] + i1[256 int]; P2: sAP[1024]

    const int tid  = threadIdx.x;
    const int lane = tid & 63, wid = tid >> 6;
    const int wcode = wid & 1, wx = wid >> 1;      // 2 code-groups(64) x 4 row-groups(32)
    const int l15 = lane & 15, l4 = lane >> 4;
    const int slice = blockIdx.x & 7, chunk = blockIdx.x >> 3;
    const int fsw = ((l4 ^ ((l15 >> 2) & 3)) << 3);

    const float* c2  = ws + WS_C2;
    const float* x2p = ws + WS_X2;

    if (PASS == 2) { sred[tid] = 0.f; sred[tid + 512] = 0.f; }

    // staging setup: 4 chunks/thread, t-invariant parts precomputed
    const ushort* sbase[4]; int sdst[4]; bool siscb[4];
    {
        const int rsub = lane >> 2, s = lane & 3;
        const int col = s ^ ((rsub >> 2) & 3);
        #pragma unroll
        for (int i = 0; i < 4; ++i) {
            int c = wid * 4 + i;
            int region = c >> 3;          // 0 cbh, 1 cbl, 2 xh, 3 xl
            int cc = c & 7;
            int row0 = cc * 16 + rsub;
            sdst[i] = region * 4096 + cc * 512;
            const ushort* arr = (region == 0) ? ch : (region == 1) ? cl
                              : (region == 2) ? xh : xl;
            int growbase = (region < 2) ? (slice * SLICE_K + row0)
                                        : (chunk * CHUNK_R + row0);
            sbase[i] = arr + (((size_t)growbase) << 8) + (col << 3);
            siscb[i] = (region < 2);
        }
    }

    do_stage(0, &lds[0][0], sbase, sdst, siscb);
    __syncthreads();

    for (int rt = 0; rt < NRT; ++rt) {
        const int rowBase = chunk * CHUNK_R + rt * BM;
        float x2v[2], bdv[2], invl[2];
        #pragma unroll
        for (int n = 0; n < 2; ++n) {
            int rl = wx * 32 + n * 16 + l15;
            x2v[n] = x2p[rowBase + rl];
            if (PASS == 2) {
                bdv[n]  = ws[WS_BD + rowBase + rl];
                invl[n] = 1.0f / ws[WS_L + rowBase + rl];
            }
        }
        float rb1[2], rb2[2], rlv[2], rTv[2]; int ri1[2];
        #pragma unroll
        for (int n = 0; n < 2; ++n) { rb1[n] = 1e30f; rb2[n] = 1e30f; rlv[n] = 0.f; rTv[n] = 0.f; ri1[n] = 0; }

        for (int kt = 0; kt < NKT; ++kt) {
            f32x4 acc[4][2];
            #pragma unroll
            for (int m = 0; m < 4; ++m)
                #pragma unroll
                for (int n = 0; n < 2; ++n) acc[m][n] = (f32x4){0.f, 0.f, 0.f, 0.f};

            #pragma unroll
            for (int dt = 0; dt < NDT; ++dt) {
                const int t = rt * 64 + kt * 8 + dt;
                if (t + 1 < NSTEP)
                    do_stage(t + 1, &lds[0][0], sbase, sdst, siscb);

                const ushort* bb = &lds[0][0] + ((t & 1) << 14);
                bf16x8 bhf[2], blf[2];
                #pragma unroll
                for (int n = 0; n < 2; ++n) {
                    int off = (wx * 32 + n * 16 + l15) * 32 + fsw;
                    bhf[n] = __builtin_bit_cast(bf16x8, *(const uint4*)(bb + 8192 + off));
                    blf[n] = __builtin_bit_cast(bf16x8, *(const uint4*)(bb + 12288 + off));
                }
                __builtin_amdgcn_s_setprio(1);
                #pragma unroll
                for (int m = 0; m < 4; ++m) {
                    int off = (wcode * 64 + m * 16 + l15) * 32 + fsw;
                    bf16x8 ahf = __builtin_bit_cast(bf16x8, *(const uint4*)(bb + off));
                    bf16x8 alf = __builtin_bit_cast(bf16x8, *(const uint4*)(bb + 4096 + off));
                    #pragma unroll
                    for (int n = 0; n < 2; ++n) {
                        acc[m][n] = __builtin_amdgcn_mfma_f32_16x16x32_bf16(ahf, bhf[n], acc[m][n], 0, 0, 0);
                        acc[m][n] = __builtin_amdgcn_mfma_f32_16x16x32_bf16(ahf, blf[n], acc[m][n], 0, 0, 0);
                        acc[m][n] = __builtin_amdgcn_mfma_f32_16x16x32_bf16(alf, bhf[n], acc[m][n], 0, 0, 0);
                    }
                }
                __builtin_amdgcn_s_setprio(0);
                __syncthreads();
            }

            // epilogue: lane holds D[code=(l4*4+r)+16m][xrow=l15+16n]
            const int cbase = slice * SLICE_K + kt * BN + wcode * 64 + l4 * 4;
            float c2v[4][4];
            #pragma unroll
            for (int m = 0; m < 4; ++m)
                #pragma unroll
                for (int r = 0; r < 4; ++r) c2v[m][r] = c2[cbase + m * 16 + r];

            if (PASS == 1) {
                #pragma unroll
                for (int n = 0; n < 2; ++n) {
                    float dsv[4][4];
                    float b1 = 1e30f, b2 = 1e30f; int i1 = 0;
                    #pragma unroll
                    for (int m = 0; m < 4; ++m)
                        #pragma unroll
                        for (int r = 0; r < 4; ++r) {
                            float d2 = fmaf(-2.f, acc[m][n][r], x2v[n] + c2v[m][r]);
                            float dv = FAST_SQRT(fmaxf(d2, 0.f));
                            dsv[m][r] = dv;
                            bool better = dv < b1;
                            b2 = better ? b1 : fminf(b2, dv);
                            if (better) { b1 = dv; i1 = cbase + m * 16 + r; }
                        }
                    float ls = 0.f, ts = 0.f;
                    #pragma unroll
                    for (int m = 0; m < 4; ++m)
                        #pragma unroll
                        for (int r = 0; r < 4; ++r) {
                            float e = __expf(b1 - dsv[m][r]);
                            ls += e;
                            ts = fmaf(e, b1 - dsv[m][r], ts);
                        }
                    online_merge(rb1[n], ri1[n], rb2[n], rlv[n], rTv[n], b1, i1, b2, ls, ts);
                }
            } else {
                float ps[4][4];
                #pragma unroll
                for (int m = 0; m < 4; ++m)
                    #pragma unroll
                    for (int r = 0; r < 4; ++r) ps[m][r] = 0.f;
                #pragma unroll
                for (int n = 0; n < 2; ++n)
                    #pragma unroll
                    for (int m = 0; m < 4; ++m)
                        #pragma unroll
                        for (int r = 0; r < 4; ++r) {
                            float d2 = fmaf(-2.f, acc[m][n][r], x2v[n] + c2v[m][r]);
                            float dv = FAST_SQRT(fmaxf(d2, 0.f));
                            ps[m][r] = fmaf(__expf(bdv[n] - dv), invl[n], ps[m][r]);
                        }
                #pragma unroll
                for (int m = 0; m < 4; ++m)
                    #pragma unroll
                    for (int r = 0; r < 4; ++r) {
                        float v = ps[m][r];
                        v += __shfl_xor(v, 1); v += __shfl_xor(v, 2);
                        v += __shfl_xor(v, 4); v += __shfl_xor(v, 8);
                        ps[m][r] = v;
                    }
                if (l15 == 0) {
                    #pragma unroll
                    for (int m = 0; m < 4; ++m)
                        #pragma unroll
                        for (int r = 0; r < 4; ++r)
                            atomicAdd(&sred[kt * BN + wcode * 64 + m * 16 + l4 * 4 + r], ps[m][r]);
                }
            }
        }

        if (PASS == 1) {
            #pragma unroll
            for (int n = 0; n < 2; ++n) {
                #pragma unroll
                for (int off = 16; off <= 32; off <<= 1) {
                    float ob1 = __shfl_xor(rb1[n], off);
                    int   oi  = __shfl_xor(ri1[n], off);
                    float ob2 = __shfl_xor(rb2[n], off);
                    float ol  = __shfl_xor(rlv[n], off);
                    float oT  = __shfl_xor(rTv[n], off);
                    online_merge(rb1[n], ri1[n], rb2[n], rlv[n], rTv[n], ob1, oi, ob2, ol, oT);
                }
            }
            if (l4 == 0) {
                #pragma unroll
                for (int n = 0; n < 2; ++n) {
                    int rl = wx * 32 + n * 16 + l15;
                    sred[(rl << 1) + wcode]       = rb1[n];
                    sred[256 + (rl << 1) + wcode] = rb2[n];
                    sred[512 + (rl << 1) + wcode] = rlv[n];
                    sred[768 + (rl << 1) + wcode] = rTv[n];
                    ((int*)sred)[1024 + (rl << 1) + wcode] = ri1[n];
                }
            }
            __syncthreads();
            if (tid < BM) {
                float b1 = sred[tid * 2];       int i1 = ((int*)sred)[1024 + tid * 2];
                float b2 = sred[256 + tid * 2];
                float L  = sred[512 + tid * 2];
                float T  = sred[768 + tid * 2];
                online_merge(b1, i1, b2, L, T,
                             sred[tid * 2 + 1], ((int*)sred)[1024 + tid * 2 + 1],
                             sred[256 + tid * 2 + 1], sred[512 + tid * 2 + 1], sred[768 + tid * 2 + 1]);
                int grow = rowBase + tid;
                P[0 * PF + slice * N_ROWS + grow] = b1;
                P[1 * PF + slice * N_ROWS + grow] = b2;
                P[2 * PF + slice * N_ROWS + grow] = L;
                P[3 * PF + slice * N_ROWS + grow] = T;
                ((int*)P)[4 * PF + slice * N_ROWS + grow] = i1;
            }
            __syncthreads();
        }
    }

    if (PASS == 2) {
        __syncthreads();
        #pragma unroll
        for (int i = 0; i < 2; ++i) {
            int k = tid + i * 512;
            atomicAdd(&ws[WS_AVGP + slice * SLICE_K + k], sred[k]);
        }
    }
}

// merge 8 slice-partials per row -> final stats + flags + entropy sum
__global__ void merge_k(const float* __restrict__ P, float* __restrict__ ws) {
    const int tid = threadIdx.x, lane = tid & 63;
    const int row = blockIdx.x * 256 + tid;
    float b1 = 1e30f, b2 = 1e30f, L = 0.f, T = 0.f; int i1 = 0;
    #pragma unroll
    for (int s = 0; s < NSLICE; ++s) {
        float nb1 = P[0 * PF + s * N_ROWS + row];
        float nb2 = P[1 * PF + s * N_ROWS + row];
        float nl  = P[2 * PF + s * N_ROWS + row];
        float nT  = P[3 * PF + s * N_ROWS + row];
        int   ni  = ((const int*)P)[4 * PF + s * N_ROWS + row];
        online_merge(b1, i1, b2, L, T, nb1, ni, nb2, nl, nT);
    }
    ws[WS_BD + row] = b1;
    ((int*)ws)[WS_BI + row] = i1;
    ws[WS_L + row] = L;
    if (b2 - b1 < TAU) {
        int p = atomicAdd(((int*)ws) + WS_FLAGN, 1);
        ((int*)ws)[WS_FLAGL + p] = row;
    }
    float sval = T / L - __logf(L);
    #pragma unroll
    for (int off = 32; off >= 1; off >>= 1) sval += __shfl_xor(sval, off);
    if (lane == 0) atomicAdd(&ws[WS_SCAL + 1], sval);
}

// exact f32 argmin recompute (d2-compare; sqrt monotone) for flagged rows
__global__ void fixup_k(const float* __restrict__ x, const float* __restrict__ cb,
                        float* __restrict__ ws) {
    __shared__ float xr[DIM];
    __shared__ float rbd[256]; __shared__ int rbi[256];
    const int tid = threadIdx.x;
    const int nf = ((const int*)ws)[WS_FLAGN];
    for (int f = blockIdx.x; f < nf; f += gridDim.x) {
        int row = ((const int*)ws)[WS_FLAGL + f];
        __syncthreads();
        if (tid < 64) ((float4*)xr)[tid] = ((const float4*)(x + (size_t)row * DIM))[tid];
        __syncthreads();
        float x2r = ws[WS_X2 + row];
        float best = 1e30f; int bi = 0;
        for (int c = tid; c < KCODES; c += 256) {
            const float4* crow = (const float4*)(cb + (size_t)c * DIM);
            float dot = 0.f;
            for (int d4 = 0; d4 < 64; ++d4) {
                float4 cv = crow[d4]; float4 xv = ((const float4*)xr)[d4];
                dot = fmaf(cv.x, xv.x, dot); dot = fmaf(cv.y, xv.y, dot);
                dot = fmaf(cv.z, xv.z, dot); dot = fmaf(cv.w, xv.w, dot);
            }
            float d2 = fmaxf(fmaf(-2.f, dot, x2r + ws[WS_C2 + c]), 0.f);
            if (d2 < best) { best = d2; bi = c; }
        }
        rbd[tid] = best; rbi[tid] = bi;
        for (int s = 128; s > 0; s >>= 1) {
            __syncthreads();
            if (tid < s) {
                float ob = rbd[tid + s]; int oi = rbi[tid + s];
                if (ob < rbd[tid] || (ob == rbd[tid] && oi < rbi[tid])) { rbd[tid] = ob; rbi[tid] = oi; }
            }
        }
        __syncthreads();
        if (tid == 0) ((int*)ws)[WS_BI + row] = rbi[0];
    }
}

__global__ void gather_k(const float* __restrict__ x, const float* __restrict__ cb,
                         float* __restrict__ ws, float* __restrict__ outQ,
                         float* __restrict__ outNcbe, float* __restrict__ outIdxF) {
    __shared__ float red2[4];
    const int tid = threadIdx.x, w = tid >> 6, lane = tid & 63;
    float msum = 0.f;
    for (int it = 0; it < 8; ++it) {
        int n = blockIdx.x * 32 + it * 4 + w;
        int idx = ((const int*)ws)[WS_BI + n];
        float4 xv = ((const float4*)(x + (size_t)n * DIM))[lane];
        float4 cv = ((const float4*)(cb + (size_t)idx * DIM))[lane];
        ((float4*)(outQ + (size_t)n * DIM))[lane] = cv;
        float* dst = outNcbe + (size_t)idx * DIM + lane * 4;
        const float g = 0.01f;
        atomicAdd(dst + 0, g * xv.x); atomicAdd(dst + 1, g * xv.y);
        atomicAdd(dst + 2, g * xv.z); atomicAdd(dst + 3, g * xv.w);
        float dx = cv.x - xv.x, dy = cv.y - xv.y, dz = cv.z - xv.z, dw = cv.w - xv.w;
        float s = dx*dx + dy*dy + dz*dz + dw*dw;
        #pragma unroll
        for (int off = 32; off >= 1; off >>= 1) s += __shfl_xor(s, off);
        if (lane == 0) {
            msum += s;
            atomicAdd(&ws[WS_CNT + idx], 1.0f);
            outIdxF[n] = (float)idx;
        }
    }
    if (lane == 0) red2[w] = msum;
    __syncthreads();
    if (tid == 0) atomicAdd(&ws[WS_SCAL + 0], red2[0] + red2[1] + red2[2] + red2[3]);
}

__global__ void stats_k(const float* __restrict__ cse, float* __restrict__ ws,
                        float* __restrict__ outNcse) {
    int tid = threadIdx.x, lane = tid & 63;
    int k = blockIdx.x * 256 + tid;
    float cnt = ws[WS_CNT + k];
    float ncse = 0.99f * cse[k] + 0.01f * cnt;
    outNcse[k] = ncse;
    float ap  = ws[WS_AVGP + k] * (1.0f / N_ROWS);
    float ae  = -(ap * __logf(ap + 1e-5f));
    float app = cnt * (1.0f / N_ROWS);
    float pe  = -(app * __logf(app + 1e-10f));
    #pragma unroll
    for (int off = 32; off >= 1; off >>= 1) {
        ncse += __shfl_xor(ncse, off);
        ae   += __shfl_xor(ae, off);
        pe   += __shfl_xor(pe, off);
    }
    if (lane == 0) {
        atomicAdd(&ws[WS_SCAL + 4], ncse);
        atomicAdd(&ws[WS_SCAL + 2], ae);
        atomicAdd(&ws[WS_SCAL + 3], pe);
    }
}

__global__ void newcb_k(const float* __restrict__ ws, const float* __restrict__ outNcse,
                        const float* __restrict__ outNcbe, float* __restrict__ outNc) {
    int w = threadIdx.x >> 6, lane = threadIdx.x & 63;
    int k = blockIdx.x * 4 + w;
    float n = ws[WS_SCAL + 4];
    float ncse = outNcse[k];
    float smoothed = (ncse + 1e-5f) / (n + (float)KCODES * 1e-5f) * n;
    float inv = 1.0f / smoothed;
    float4 v = ((const float4*)(outNcbe + (size_t)k * DIM))[lane];
    v.x *= inv; v.y *= inv; v.z *= inv; v.w *= inv;
    ((float4*)(outNc + (size_t)k * DIM))[lane] = v;
}

__global__ void finalize_k(const float* __restrict__ ws, float* __restrict__ outLoss,
                           float* __restrict__ outPerp) {
    float mse  = ws[WS_SCAL + 0] * (1.0f / ((float)N_ROWS * 256.0f));
    float sent = -ws[WS_SCAL + 1] * (1.0f / (float)N_ROWS);
    float ent  = sent - ws[WS_SCAL + 2];
    outLoss[0] = 1.25f * mse + 0.1f * ent;
    outPerp[0] = expf(ws[WS_SCAL + 3]);
}

extern "C" void kernel_launch(void* const* d_in, const int* in_sizes, int n_in,
                              void* d_out, int out_size, void* d_ws, size_t ws_size,
                              hipStream_t stream) {
    const float* x   = (const float*)d_in[0];
    const float* cb  = (const float*)d_in[1];
    const float* cse = (const float*)d_in[2];
    const float* cbe = (const float*)d_in[3];
    float* out = (float*)d_out;
    float* ws  = (float*)d_ws;

    float* outQ    = out;
    float* outLoss = out + 8388608;
    float* outPerp = out + 8388609;
    float* outIdxF = out + 8388610;
    float* outNc   = out + 8421378;
    float* outNcse = out + 10518530;
    float* outNcbe = out + 10526722;

    // scratch inside d_out: x splits in outQ, cb splits in outNc(+2 align), partials in outNcbe
    ushort* xh = (ushort*)outQ;
    ushort* xl = xh + (size_t)N_ROWS * DIM;
    ushort* ch = (ushort*)(out + 8421380);
    ushort* cl = ch + (size_t)KCODES * DIM;
    float*  P  = outNcbe;   // 5*PF floats = 5.24 MB

    hipMemsetAsync(ws + WS_AVGP, 0, (size_t)(WS_FLAGN + 1 - WS_AVGP) * sizeof(float), stream);
    rownorm_k<<<KCODES / 4, 256, 0, stream>>>(cb, ws + WS_C2, KCODES);
    rownorm_k<<<N_ROWS / 4, 256, 0, stream>>>(x, ws + WS_X2, N_ROWS);
    split_k<<<N_ROWS * DIM / 8 / 256, 256, 0, stream>>>(x, xh, xl);
    split_k<<<KCODES * DIM / 8 / 256, 256, 0, stream>>>(cb, ch, cl);
    vq_mfma<1><<<NSLICE * (N_ROWS / CHUNK_R), 512, 0, stream>>>(xh, xl, ch, cl, ws, P);
    merge_k<<<N_ROWS / 256, 256, 0, stream>>>(P, ws);
    vq_mfma<2><<<NSLICE * (N_ROWS / CHUNK_R), 512, 0, stream>>>(xh, xl, ch, cl, ws, P);
    fixup_k<<<512, 256, 0, stream>>>(x, cb, ws);
    init_ncbe_k<<<2048, 256, 0, stream>>>(cbe, outNcbe);
    gather_k<<<1024, 256, 0, stream>>>(x, cb, ws, outQ, outNcbe, outIdxF);
    stats_k<<<KCODES / 256, 256, 0, stream>>>(cse, ws, outNcse);
    newcb_k<<<KCODES / 4, 256, 0, stream>>>(ws, outNcse, outNcbe, outNc);
    finalize_k<<<1, 1, 0, stream>>>(ws, outLoss, outPerp);
}